// Round 3
// baseline (1257.777 us; speedup 1.0000x reference)
//
#include <hip/hip_runtime.h>
#include <hip/hip_bf16.h>

#define N_NODES 50000
#define F_IN 128
#define HID 128
#define N_OUT 16
#define HEADS 4
#define EL 800000
#define EG 200000
#define NEG_SLOPE 0.2f

// ---------- helpers ----------
static __device__ __forceinline__ unsigned ford(float f) {
    unsigned u = __float_as_uint(f);
    return (u & 0x80000000u) ? ~u : (u | 0x80000000u);
}
static __device__ __forceinline__ float ford_inv(unsigned u) {
    unsigned b = (u & 0x80000000u) ? (u ^ 0x80000000u) : ~u;
    return __uint_as_float(b);
}
static __device__ __forceinline__ float lrelu(float x) {
    return x > 0.f ? x : NEG_SLOPE * x;
}

// ---------- generic f32 tiled GEMM: C[M,N] = act(A[M,K] @ B[K,N] + bias) ----------
__global__ __launch_bounds__(256) void gemm_f32(
    const float* __restrict__ A, const float* __restrict__ B,
    const float* __restrict__ bias, float* __restrict__ C,
    int M, int K, int Ncols, int relu_act)
{
    __shared__ float As[32][68];
    __shared__ float Bs[32][68];
    int tid = threadIdx.x;
    int tx = tid & 15, ty = tid >> 4;
    int m0 = blockIdx.x * 64;
    int n0 = blockIdx.y * 64;
    float acc[4][4] = {};
    for (int kt = 0; kt < K; kt += 32) {
        #pragma unroll
        for (int i = 0; i < 2; i++) {
            int idx = tid + i * 256;          // 0..511
            int row = idx >> 3;               // 64 rows, 8 float4/row
            int k4  = (idx & 7) << 2;
            float4 v = make_float4(0.f, 0.f, 0.f, 0.f);
            int gr = m0 + row;
            if (gr < M) v = *(const float4*)(A + (size_t)gr * K + kt + k4);
            As[k4 + 0][row] = v.x; As[k4 + 1][row] = v.y;
            As[k4 + 2][row] = v.z; As[k4 + 3][row] = v.w;
        }
        #pragma unroll
        for (int i = 0; i < 2; i++) {
            int idx = tid + i * 256;
            int kk = idx >> 4;                // 32 rows, 16 float4/row
            int c4 = (idx & 15) << 2;
            *(float4*)&Bs[kk][c4] = *(const float4*)(B + (size_t)(kt + kk) * Ncols + n0 + c4);
        }
        __syncthreads();
        #pragma unroll
        for (int kk = 0; kk < 32; kk++) {
            float4 a4 = *(const float4*)&As[kk][ty << 2];
            float4 b4 = *(const float4*)&Bs[kk][tx << 2];
            float av[4] = {a4.x, a4.y, a4.z, a4.w};
            float bv[4] = {b4.x, b4.y, b4.z, b4.w};
            #pragma unroll
            for (int i = 0; i < 4; i++)
                #pragma unroll
                for (int j = 0; j < 4; j++)
                    acc[i][j] = fmaf(av[i], bv[j], acc[i][j]);
        }
        __syncthreads();
    }
    #pragma unroll
    for (int i = 0; i < 4; i++) {
        int gr = m0 + (ty << 2) + i;
        if (gr >= M) continue;
        #pragma unroll
        for (int j = 0; j < 4; j++) {
            int gc = n0 + (tx << 2) + j;
            float v = acc[i][j];
            if (bias) v += bias[gc];
            if (relu_act) v = fmaxf(v, 0.f);
            C[(size_t)gr * Ncols + gc] = v;
        }
    }
}

// ---------- fused pooled GEMM + column-mean accumulation ----------
__global__ __launch_bounds__(256) void pooled_mean(
    const float* __restrict__ Xlg, const float* __restrict__ Xgg,
    const float* __restrict__ Wp, const float* __restrict__ bp,
    float* __restrict__ sumvec)
{
    __shared__ float As[32][68];
    __shared__ float Bs[32][68];
    __shared__ float red[16][68];
    int tid = threadIdx.x;
    int tx = tid & 15, ty = tid >> 4;
    int m0 = blockIdx.x * 64;
    int n0 = blockIdx.y * 64;
    float acc[4][4] = {};
    for (int kt = 0; kt < 256; kt += 32) {
        const float* Asrc = (kt < 128) ? Xlg : Xgg;
        int kb = (kt < 128) ? kt : kt - 128;
        #pragma unroll
        for (int i = 0; i < 2; i++) {
            int idx = tid + i * 256;
            int row = idx >> 3;
            int k4  = (idx & 7) << 2;
            float4 v = make_float4(0.f, 0.f, 0.f, 0.f);
            int gr = m0 + row;
            if (gr < N_NODES) v = *(const float4*)(Asrc + (size_t)gr * HID + kb + k4);
            As[k4 + 0][row] = v.x; As[k4 + 1][row] = v.y;
            As[k4 + 2][row] = v.z; As[k4 + 3][row] = v.w;
        }
        #pragma unroll
        for (int i = 0; i < 2; i++) {
            int idx = tid + i * 256;
            int kk = idx >> 4;
            int c4 = (idx & 15) << 2;
            *(float4*)&Bs[kk][c4] = *(const float4*)(Wp + (size_t)(kt + kk) * HID + n0 + c4);
        }
        __syncthreads();
        #pragma unroll
        for (int kk = 0; kk < 32; kk++) {
            float4 a4 = *(const float4*)&As[kk][ty << 2];
            float4 b4 = *(const float4*)&Bs[kk][tx << 2];
            float av[4] = {a4.x, a4.y, a4.z, a4.w};
            float bv[4] = {b4.x, b4.y, b4.z, b4.w};
            #pragma unroll
            for (int i = 0; i < 4; i++)
                #pragma unroll
                for (int j = 0; j < 4; j++)
                    acc[i][j] = fmaf(av[i], bv[j], acc[i][j]);
        }
        __syncthreads();
    }
    float cs[4] = {0.f, 0.f, 0.f, 0.f};
    #pragma unroll
    for (int i = 0; i < 4; i++) {
        int gr = m0 + (ty << 2) + i;
        if (gr >= N_NODES) continue;
        #pragma unroll
        for (int j = 0; j < 4; j++) {
            int gc = n0 + (tx << 2) + j;
            float v = fmaxf(acc[i][j] + bp[gc], 0.f);
            cs[j] += v;
        }
    }
    *(float4*)&red[ty][tx << 2] = make_float4(cs[0], cs[1], cs[2], cs[3]);
    __syncthreads();
    if (tid < 64) {
        float s = 0.f;
        #pragma unroll
        for (int t = 0; t < 16; t++) s += red[t][tid];
        atomicAdd(&sumvec[n0 + tid], s);
    }
}

// ---------- GCN ----------
__global__ void deg_init(float* __restrict__ deg) {
    int i = blockIdx.x * blockDim.x + threadIdx.x;
    if (i < N_NODES) deg[i] = 1.0f;   // self loop
}
__global__ void deg_count(const int* __restrict__ dst, float* __restrict__ deg) {
    int e = blockIdx.x * blockDim.x + threadIdx.x;
    if (e < EL) atomicAdd(&deg[dst[e]], 1.0f);
}
__global__ void deg_rsqrt(float* __restrict__ deg) {
    int i = blockIdx.x * blockDim.x + threadIdx.x;
    if (i < N_NODES) deg[i] = rsqrtf(fmaxf(deg[i], 1e-12f));
}
__global__ __launch_bounds__(256) void gcn_scatter(
    const int* __restrict__ src, const int* __restrict__ dst,
    const float* __restrict__ xw, const float* __restrict__ dinv,
    float* __restrict__ acc)
{
    int lane = threadIdx.x & 63;
    int gw = (blockIdx.x * 256 + threadIdx.x) >> 6;
    int nw = gridDim.x * 4;
    for (int e = gw; e < EL; e += nw) {
        int s = src[e], d = dst[e];
        float nrm = dinv[s] * dinv[d];
        float2 v = *(const float2*)(xw + (size_t)s * HID + lane * 2);
        atomicAdd(&acc[(size_t)d * HID + lane * 2],     v.x * nrm);
        atomicAdd(&acc[(size_t)d * HID + lane * 2 + 1], v.y * nrm);
    }
}
__global__ void gcn_finalize(const float* __restrict__ xw, const float* __restrict__ dinv,
                             const float* __restrict__ bg, float* __restrict__ xlg)
{
    int idx = blockIdx.x * blockDim.x + threadIdx.x;   // over N*32 float4s
    if (idx >= N_NODES * 32) return;
    int n = idx >> 5, c4 = (idx & 31) << 2;
    float dv = dinv[n]; float self = dv * dv;
    float4 a = *(const float4*)(xlg + (size_t)n * HID + c4);
    float4 g = *(const float4*)(xw  + (size_t)n * HID + c4);
    float4 b = *(const float4*)(bg + c4);
    float4 o;
    o.x = fmaxf(a.x + g.x * self + b.x, 0.f);
    o.y = fmaxf(a.y + g.y * self + b.y, 0.f);
    o.z = fmaxf(a.z + g.z * self + b.z, 0.f);
    o.w = fmaxf(a.w + g.w * self + b.w, 0.f);
    *(float4*)(xlg + (size_t)n * HID + c4) = o;
}

// ---------- GAT ----------
__global__ __launch_bounds__(256) void attn_coef(
    const float* __restrict__ xw, const float* __restrict__ atts, const float* __restrict__ attd,
    float* __restrict__ a_s, float* __restrict__ a_d)
{
    int lane = threadIdx.x & 63;
    int wid = (blockIdx.x * 256 + threadIdx.x) >> 6;
    float s8[8], d8[8];
    #pragma unroll
    for (int j = 0; j < 8; j++) { s8[j] = atts[lane * 8 + j]; d8[j] = attd[lane * 8 + j]; }
    if (wid >= N_NODES) return;
    const float* p = xw + (size_t)wid * 512 + lane * 8;
    float4 v0 = *(const float4*)p, v1 = *(const float4*)(p + 4);
    float vv[8] = {v0.x, v0.y, v0.z, v0.w, v1.x, v1.y, v1.z, v1.w};
    float ps = 0.f, pd = 0.f;
    #pragma unroll
    for (int j = 0; j < 8; j++) { ps = fmaf(vv[j], s8[j], ps); pd = fmaf(vv[j], d8[j], pd); }
    #pragma unroll
    for (int off = 1; off < 16; off <<= 1) { ps += __shfl_xor(ps, off); pd += __shfl_xor(pd, off); }
    if ((lane & 15) == 0) {
        int h = lane >> 4;
        a_s[wid * 4 + h] = ps;
        a_d[wid * 4 + h] = pd;
    }
}
__global__ void gat_node_init(const float* __restrict__ a_s, const float* __restrict__ a_d,
                              unsigned* __restrict__ emax)
{
    int i = blockIdx.x * blockDim.x + threadIdx.x;   // N*4
    if (i >= N_NODES * 4) return;
    emax[i] = ford(lrelu(a_s[i] + a_d[i]));          // self loop
}
__global__ void gat_edge_max(const int* __restrict__ src, const int* __restrict__ dst,
                             const float* __restrict__ a_s, const float* __restrict__ a_d,
                             float* __restrict__ estore, unsigned* __restrict__ emax)
{
    int e = blockIdx.x * blockDim.x + threadIdx.x;
    if (e >= EG) return;
    int s = src[e], d = dst[e];
    float4 as4 = *(const float4*)(a_s + (size_t)s * 4);
    float4 ad4 = *(const float4*)(a_d + (size_t)d * 4);
    float ev[4] = {as4.x + ad4.x, as4.y + ad4.y, as4.z + ad4.z, as4.w + ad4.w};
    #pragma unroll
    for (int h = 0; h < 4; h++) {
        float x = lrelu(ev[h]);
        estore[(size_t)e * 4 + h] = x;
        atomicMax(&emax[(size_t)d * 4 + h], ford(x));
    }
}
__global__ void gat_node_denom(const float* __restrict__ a_s, const float* __restrict__ a_d,
                               const unsigned* __restrict__ emax, float* __restrict__ denom)
{
    int i = blockIdx.x * blockDim.x + threadIdx.x;
    if (i >= N_NODES * 4) return;
    float x = lrelu(a_s[i] + a_d[i]);
    denom[i] = expf(x - ford_inv(emax[i]));
}
__global__ void gat_edge_expsum(const int* __restrict__ dst, const unsigned* __restrict__ emax,
                                float* __restrict__ estore, float* __restrict__ denom)
{
    int e = blockIdx.x * blockDim.x + threadIdx.x;
    if (e >= EG) return;
    int d = dst[e];
    #pragma unroll
    for (int h = 0; h < 4; h++) {
        float m = ford_inv(emax[(size_t)d * 4 + h]);
        float ee = expf(estore[(size_t)e * 4 + h] - m);
        estore[(size_t)e * 4 + h] = ee;
        atomicAdd(&denom[(size_t)d * 4 + h], ee);
    }
}
__global__ void gat_gg_init(const float* __restrict__ a_s, const float* __restrict__ a_d,
                            const unsigned* __restrict__ emax, const float* __restrict__ denom,
                            const float* __restrict__ xw, float* __restrict__ gg)
{
    int idx = blockIdx.x * blockDim.x + threadIdx.x;   // N*128
    if (idx >= N_NODES * HID) return;
    int n = idx >> 7, c = idx & 127;
    float acc = 0.f;
    #pragma unroll
    for (int h = 0; h < 4; h++) {
        float x = lrelu(a_s[n * 4 + h] + a_d[n * 4 + h]);
        float alpha = expf(x - ford_inv(emax[n * 4 + h])) / (denom[n * 4 + h] + 1e-16f);
        acc = fmaf(xw[(size_t)n * 512 + h * 128 + c], alpha, acc);
    }
    gg[idx] = acc;
}
__global__ __launch_bounds__(256) void gat_scatter(
    const int* __restrict__ src, const int* __restrict__ dst,
    const float* __restrict__ estore, const float* __restrict__ denom,
    const float* __restrict__ xw, float* __restrict__ gg)
{
    int lane = threadIdx.x & 63;
    int gw = (blockIdx.x * 256 + threadIdx.x) >> 6;
    int nw = gridDim.x * 4;
    for (int e = gw; e < EG; e += nw) {
        int s = src[e], d = dst[e];
        float4 ee = *(const float4*)(estore + (size_t)e * 4);
        float4 dn = *(const float4*)(denom + (size_t)d * 4);
        float al[4] = {ee.x / (dn.x + 1e-16f), ee.y / (dn.y + 1e-16f),
                       ee.z / (dn.z + 1e-16f), ee.w / (dn.w + 1e-16f)};
        int c = lane * 2;
        float r0 = 0.f, r1 = 0.f;
        #pragma unroll
        for (int h = 0; h < 4; h++) {
            float2 v = *(const float2*)(xw + (size_t)s * 512 + h * 128 + c);
            r0 = fmaf(v.x, al[h], r0);
            r1 = fmaf(v.y, al[h], r1);
        }
        atomicAdd(&gg[(size_t)d * HID + c],     r0);
        atomicAdd(&gg[(size_t)d * HID + c + 1], r1);
    }
}
__global__ void gat_finalize(const float* __restrict__ ba, float* __restrict__ gg)
{
    int idx = blockIdx.x * blockDim.x + threadIdx.x;   // N*32 float4s
    if (idx >= N_NODES * 32) return;
    int c4 = (idx & 31) << 2;
    float4 v = *(const float4*)(gg + (size_t)(idx >> 5) * HID + c4);
    float4 b = *(const float4*)(ba + c4);
    float4 o;
    o.x = fmaxf(v.x * 0.25f + b.x, 0.f);
    o.y = fmaxf(v.y * 0.25f + b.y, 0.f);
    o.z = fmaxf(v.z * 0.25f + b.z, 0.f);
    o.w = fmaxf(v.w * 0.25f + b.w, 0.f);
    *(float4*)(gg + (size_t)(idx >> 5) * HID + c4) = o;
}

// ---------- final heads (f32 output!) ----------
__global__ void final_head(const float* __restrict__ sumvec,
                           const float* __restrict__ Wc1, const float* __restrict__ bc1,
                           const float* __restrict__ Wc2, const float* __restrict__ bc2,
                           const float* __restrict__ Wu, const float* __restrict__ bu,
                           float* __restrict__ out)
{
    __shared__ float xf[128];
    __shared__ float h1[64];
    int t = threadIdx.x;   // 128 threads
    xf[t] = sumvec[t] * (1.0f / N_NODES);
    __syncthreads();
    if (t < 64) {
        float s = bc1[t];
        for (int c = 0; c < 128; c++) s = fmaf(xf[c], Wc1[c * 64 + t], s);
        h1[t] = fmaxf(s, 0.f);
    }
    __syncthreads();
    if (t < 16) {
        float s = bc2[t];
        for (int j = 0; j < 64; j++) s = fmaf(h1[j], Wc2[j * 16 + t], s);
        out[t] = s;
        float u = bu[t];
        for (int c = 0; c < 128; c++) u = fmaf(xf[c], Wu[c * 16 + t], u);
        out[16 + t] = 1.0f / (1.0f + expf(-u));
    }
}

extern "C" void kernel_launch(void* const* d_in, const int* in_sizes, int n_in,
                              void* d_out, int out_size, void* d_ws, size_t ws_size,
                              hipStream_t stream) {
    const float* x    = (const float*)d_in[0];
    const int*   lei  = (const int*)d_in[1];
    const int*   gei  = (const int*)d_in[2];
    const float* W1   = (const float*)d_in[3];
    const float* b1   = (const float*)d_in[4];
    const float* Wg   = (const float*)d_in[5];
    const float* bg   = (const float*)d_in[6];
    const float* Wa   = (const float*)d_in[7];
    const float* atts = (const float*)d_in[8];
    const float* attd = (const float*)d_in[9];
    const float* ba   = (const float*)d_in[10];
    const float* Wp   = (const float*)d_in[11];
    const float* bp   = (const float*)d_in[12];
    const float* Wc1  = (const float*)d_in[13];
    const float* bc1  = (const float*)d_in[14];
    const float* Wc2  = (const float*)d_in[15];
    const float* bc2  = (const float*)d_in[16];
    const float* Wu   = (const float*)d_in[17];
    const float* bu   = (const float*)d_in[18];

    const int* lsrc = lei;
    const int* ldst = lei + EL;
    const int* gsrc = gei;
    const int* gdst = gei + EG;

    uintptr_t base = (uintptr_t)d_ws;
    auto alloc = [&](size_t bytes) { void* p = (void*)base; base += (bytes + 255) & ~(size_t)255; return p; };
    float*    x_local = (float*)alloc((size_t)N_NODES * HID * 4);
    float*    x_lg    = (float*)alloc((size_t)N_NODES * HID * 4);
    float*    x_gg    = (float*)alloc((size_t)N_NODES * HID * 4);
    float*    big     = (float*)alloc((size_t)N_NODES * 512 * 4);   // xw_g then xw_a
    float*    deg     = (float*)alloc((size_t)N_NODES * 4);
    float*    a_s     = (float*)alloc((size_t)N_NODES * 4 * 4);
    float*    a_d     = (float*)alloc((size_t)N_NODES * 4 * 4);
    unsigned* emax    = (unsigned*)alloc((size_t)N_NODES * 4 * 4);
    float*    denom   = (float*)alloc((size_t)N_NODES * 4 * 4);
    float*    estore  = (float*)alloc((size_t)EG * 4 * 4);
    float*    sumvec  = (float*)alloc(128 * 4);

    hipMemsetAsync(x_lg, 0, (size_t)N_NODES * HID * 4, stream);
    hipMemsetAsync(sumvec, 0, 128 * 4, stream);

    // x_local = relu(x @ W1 + b1)
    gemm_f32<<<dim3(782, 2), 256, 0, stream>>>(x, W1, b1, x_local, N_NODES, 128, 128, 1);

    // ---- GCN branch ----
    gemm_f32<<<dim3(782, 2), 256, 0, stream>>>(x_local, Wg, nullptr, big, N_NODES, 128, 128, 0);
    deg_init<<<196, 256, 0, stream>>>(deg);
    deg_count<<<3125, 256, 0, stream>>>(ldst, deg);
    deg_rsqrt<<<196, 256, 0, stream>>>(deg);
    gcn_scatter<<<4096, 256, 0, stream>>>(lsrc, ldst, big, deg, x_lg);
    gcn_finalize<<<6250, 256, 0, stream>>>(big, deg, bg, x_lg);

    // ---- GAT branch ----
    gemm_f32<<<dim3(782, 8), 256, 0, stream>>>(x_local, Wa, nullptr, big, N_NODES, 128, 512, 0);
    attn_coef<<<12500, 256, 0, stream>>>(big, atts, attd, a_s, a_d);
    gat_node_init<<<782, 256, 0, stream>>>(a_s, a_d, emax);
    gat_edge_max<<<782, 256, 0, stream>>>(gsrc, gdst, a_s, a_d, estore, emax);
    gat_node_denom<<<782, 256, 0, stream>>>(a_s, a_d, emax, denom);
    gat_edge_expsum<<<782, 256, 0, stream>>>(gdst, emax, estore, denom);
    gat_gg_init<<<25000, 256, 0, stream>>>(a_s, a_d, emax, denom, big, x_gg);
    gat_scatter<<<2048, 256, 0, stream>>>(gsrc, gdst, estore, denom, big, x_gg);
    gat_finalize<<<6250, 256, 0, stream>>>(ba, x_gg);

    // ---- pool + heads ----
    pooled_mean<<<dim3(782, 2), 256, 0, stream>>>(x_lg, x_gg, Wp, bp, sumvec);
    final_head<<<1, 128, 0, stream>>>(sumvec, Wc1, bc1, Wc2, bc2, Wu, bu,
                                      (float*)d_out);
}

// Round 4
// 533.357 us; speedup vs baseline: 2.3582x; 2.3582x over previous
//
#include <hip/hip_runtime.h>
#include <hip/hip_bf16.h>

#define N_NODES 50000
#define F_IN 128
#define HID 128
#define N_OUT 16
#define HEADS 4
#define EL 800000
#define EG 200000
#define NEG_SLOPE 0.2f

static __device__ __forceinline__ float lrelu(float x) {
    return x > 0.f ? x : NEG_SLOPE * x;
}

// ---------- generic f32 tiled GEMM: C[M,N] = act(A[M,K] @ B[K,N] + bias) ----------
__global__ __launch_bounds__(256) void gemm_f32(
    const float* __restrict__ A, const float* __restrict__ B,
    const float* __restrict__ bias, float* __restrict__ C,
    int M, int K, int Ncols, int relu_act)
{
    __shared__ float As[32][68];
    __shared__ float Bs[32][68];
    int tid = threadIdx.x;
    int tx = tid & 15, ty = tid >> 4;
    int m0 = blockIdx.x * 64;
    int n0 = blockIdx.y * 64;
    float acc[4][4] = {};
    for (int kt = 0; kt < K; kt += 32) {
        #pragma unroll
        for (int i = 0; i < 2; i++) {
            int idx = tid + i * 256;          // 0..511
            int row = idx >> 3;               // 64 rows, 8 float4/row
            int k4  = (idx & 7) << 2;
            float4 v = make_float4(0.f, 0.f, 0.f, 0.f);
            int gr = m0 + row;
            if (gr < M) v = *(const float4*)(A + (size_t)gr * K + kt + k4);
            As[k4 + 0][row] = v.x; As[k4 + 1][row] = v.y;
            As[k4 + 2][row] = v.z; As[k4 + 3][row] = v.w;
        }
        #pragma unroll
        for (int i = 0; i < 2; i++) {
            int idx = tid + i * 256;
            int kk = idx >> 4;                // 32 rows, 16 float4/row
            int c4 = (idx & 15) << 2;
            *(float4*)&Bs[kk][c4] = *(const float4*)(B + (size_t)(kt + kk) * Ncols + n0 + c4);
        }
        __syncthreads();
        #pragma unroll
        for (int kk = 0; kk < 32; kk++) {
            float4 a4 = *(const float4*)&As[kk][ty << 2];
            float4 b4 = *(const float4*)&Bs[kk][tx << 2];
            float av[4] = {a4.x, a4.y, a4.z, a4.w};
            float bv[4] = {b4.x, b4.y, b4.z, b4.w};
            #pragma unroll
            for (int i = 0; i < 4; i++)
                #pragma unroll
                for (int j = 0; j < 4; j++)
                    acc[i][j] = fmaf(av[i], bv[j], acc[i][j]);
        }
        __syncthreads();
    }
    #pragma unroll
    for (int i = 0; i < 4; i++) {
        int gr = m0 + (ty << 2) + i;
        if (gr >= M) continue;
        #pragma unroll
        for (int j = 0; j < 4; j++) {
            int gc = n0 + (tx << 2) + j;
            float v = acc[i][j];
            if (bias) v += bias[gc];
            if (relu_act) v = fmaxf(v, 0.f);
            C[(size_t)gr * Ncols + gc] = v;
        }
    }
}

// ---------- fused pooled GEMM + column-mean accumulation ----------
__global__ __launch_bounds__(256) void pooled_mean(
    const float* __restrict__ Xlg, const float* __restrict__ Xgg,
    const float* __restrict__ Wp, const float* __restrict__ bp,
    float* __restrict__ sumvec)
{
    __shared__ float As[32][68];
    __shared__ float Bs[32][68];
    __shared__ float red[16][68];
    int tid = threadIdx.x;
    int tx = tid & 15, ty = tid >> 4;
    int m0 = blockIdx.x * 64;
    int n0 = blockIdx.y * 64;
    float acc[4][4] = {};
    for (int kt = 0; kt < 256; kt += 32) {
        const float* Asrc = (kt < 128) ? Xlg : Xgg;
        int kb = (kt < 128) ? kt : kt - 128;
        #pragma unroll
        for (int i = 0; i < 2; i++) {
            int idx = tid + i * 256;
            int row = idx >> 3;
            int k4  = (idx & 7) << 2;
            float4 v = make_float4(0.f, 0.f, 0.f, 0.f);
            int gr = m0 + row;
            if (gr < N_NODES) v = *(const float4*)(Asrc + (size_t)gr * HID + kb + k4);
            As[k4 + 0][row] = v.x; As[k4 + 1][row] = v.y;
            As[k4 + 2][row] = v.z; As[k4 + 3][row] = v.w;
        }
        #pragma unroll
        for (int i = 0; i < 2; i++) {
            int idx = tid + i * 256;
            int kk = idx >> 4;
            int c4 = (idx & 15) << 2;
            *(float4*)&Bs[kk][c4] = *(const float4*)(Wp + (size_t)(kt + kk) * HID + n0 + c4);
        }
        __syncthreads();
        #pragma unroll
        for (int kk = 0; kk < 32; kk++) {
            float4 a4 = *(const float4*)&As[kk][ty << 2];
            float4 b4 = *(const float4*)&Bs[kk][tx << 2];
            float av[4] = {a4.x, a4.y, a4.z, a4.w};
            float bv[4] = {b4.x, b4.y, b4.z, b4.w};
            #pragma unroll
            for (int i = 0; i < 4; i++)
                #pragma unroll
                for (int j = 0; j < 4; j++)
                    acc[i][j] = fmaf(av[i], bv[j], acc[i][j]);
        }
        __syncthreads();
    }
    float cs[4] = {0.f, 0.f, 0.f, 0.f};
    #pragma unroll
    for (int i = 0; i < 4; i++) {
        int gr = m0 + (ty << 2) + i;
        if (gr >= N_NODES) continue;
        #pragma unroll
        for (int j = 0; j < 4; j++) {
            int gc = n0 + (tx << 2) + j;
            float v = fmaxf(acc[i][j] + bp[gc], 0.f);
            cs[j] += v;
        }
    }
    *(float4*)&red[ty][tx << 2] = make_float4(cs[0], cs[1], cs[2], cs[3]);
    __syncthreads();
    if (tid < 64) {
        float s = 0.f;
        #pragma unroll
        for (int t = 0; t < 16; t++) s += red[t][tid];
        atomicAdd(&sumvec[n0 + tid], s);
    }
}

// ---------- CSR build ----------
__global__ void hist_kernel(const int* __restrict__ dst, int nE, int* __restrict__ hist) {
    int e = blockIdx.x * 256 + threadIdx.x;
    if (e < nE) atomicAdd(&hist[dst[e]], 1);
}
// per-block sums of 256 hist entries
__global__ void scan_partial(const int* __restrict__ hist, int n, int* __restrict__ bsum) {
    __shared__ int s[256];
    int i = blockIdx.x * 256 + threadIdx.x;
    s[threadIdx.x] = (i < n) ? hist[i] : 0;
    __syncthreads();
    for (int off = 128; off > 0; off >>= 1) {
        if (threadIdx.x < off) s[threadIdx.x] += s[threadIdx.x + off];
        __syncthreads();
    }
    if (threadIdx.x == 0) bsum[blockIdx.x] = s[0];
}
// exclusive scan of up to 256 block sums, single block
__global__ void scan_bsums(int* __restrict__ bsum, int nb) {
    __shared__ int s[256];
    int t = threadIdx.x;
    s[t] = (t < nb) ? bsum[t] : 0;
    __syncthreads();
    for (int off = 1; off < 256; off <<= 1) {
        int v = (t >= off) ? s[t - off] : 0;
        __syncthreads();
        s[t] += v;
        __syncthreads();
    }
    if (t < nb) bsum[t] = (t == 0) ? 0 : s[t - 1];
}
// final exclusive offsets
__global__ void scan_final(const int* __restrict__ hist, int n,
                           const int* __restrict__ bsum, int* __restrict__ offs, int total) {
    __shared__ int s[256];
    int t = threadIdx.x, i = blockIdx.x * 256 + t;
    int v = (i < n) ? hist[i] : 0;
    s[t] = v;
    __syncthreads();
    for (int off = 1; off < 256; off <<= 1) {
        int u = (t >= off) ? s[t - off] : 0;
        __syncthreads();
        s[t] += u;
        __syncthreads();
    }
    if (i < n) offs[i] = bsum[blockIdx.x] + s[t] - v;
    if (i == n - 1) offs[n] = total;
}
__global__ void fill_csr(const int* __restrict__ src, const int* __restrict__ dst, int nE,
                         const int* __restrict__ offs, int* __restrict__ cursor,
                         int* __restrict__ csr) {
    int e = blockIdx.x * 256 + threadIdx.x;
    if (e >= nE) return;
    int d = dst[e];
    int r = atomicAdd(&cursor[d], 1);
    csr[offs[d] + r] = src[e];
}
__global__ void dinv_from_offs(const int* __restrict__ offs, float* __restrict__ dinv) {
    int i = blockIdx.x * 256 + threadIdx.x;
    if (i < N_NODES) dinv[i] = rsqrtf((float)(offs[i + 1] - offs[i] + 1));
}

// ---------- GCN gather (fused normalize + self loop + bias + relu) ----------
__global__ __launch_bounds__(256) void gcn_gather(
    const int* __restrict__ offs, const int* __restrict__ csr,
    const float* __restrict__ xw, const float* __restrict__ dinv,
    const float* __restrict__ bg, float* __restrict__ out)
{
    int lane = threadIdx.x & 63;
    int d = (blockIdx.x * 256 + threadIdx.x) >> 6;
    if (d >= N_NODES) return;
    int base = offs[d], end = offs[d + 1];
    int c2 = lane * 2;
    float2 acc = make_float2(0.f, 0.f);
    int i = base;
    while (i < end) {
        int chunk = min(64, end - i);
        int sv = 0; float dvv = 0.f;
        if (lane < chunk) { sv = csr[i + lane]; dvv = dinv[sv]; }
        for (int j = 0; j < chunk; j++) {
            int s = __shfl(sv, j);
            float dv = __shfl(dvv, j);
            float2 v = *(const float2*)(xw + (size_t)s * HID + c2);
            acc.x = fmaf(v.x, dv, acc.x);
            acc.y = fmaf(v.y, dv, acc.y);
        }
        i += chunk;
    }
    float dd = dinv[d];
    float2 selfv = *(const float2*)(xw + (size_t)d * HID + c2);
    float2 b2 = *(const float2*)(bg + c2);
    float2 o;
    o.x = fmaxf(dd * acc.x + dd * dd * selfv.x + b2.x, 0.f);
    o.y = fmaxf(dd * acc.y + dd * dd * selfv.y + b2.y, 0.f);
    *(float2*)(out + (size_t)d * HID + c2) = o;
}

// ---------- GAT ----------
__global__ __launch_bounds__(256) void attn_coef(
    const float* __restrict__ xw, const float* __restrict__ atts, const float* __restrict__ attd,
    float* __restrict__ a_s, float* __restrict__ a_d)
{
    int lane = threadIdx.x & 63;
    int wid = (blockIdx.x * 256 + threadIdx.x) >> 6;
    float s8[8], d8[8];
    #pragma unroll
    for (int j = 0; j < 8; j++) { s8[j] = atts[lane * 8 + j]; d8[j] = attd[lane * 8 + j]; }
    if (wid >= N_NODES) return;
    const float* p = xw + (size_t)wid * 512 + lane * 8;
    float4 v0 = *(const float4*)p, v1 = *(const float4*)(p + 4);
    float vv[8] = {v0.x, v0.y, v0.z, v0.w, v1.x, v1.y, v1.z, v1.w};
    float ps = 0.f, pd = 0.f;
    #pragma unroll
    for (int j = 0; j < 8; j++) { ps = fmaf(vv[j], s8[j], ps); pd = fmaf(vv[j], d8[j], pd); }
    #pragma unroll
    for (int off = 1; off < 16; off <<= 1) { ps += __shfl_xor(ps, off); pd += __shfl_xor(pd, off); }
    if ((lane & 15) == 0) {
        int h = lane >> 4;
        a_s[wid * 4 + h] = ps;
        a_d[wid * 4 + h] = pd;
    }
}

// per-node edge softmax over CSR; writes per-slot alpha4 and alpha_self4
__global__ void gat_softmax(const int* __restrict__ offs, const int* __restrict__ csr,
                            const float* __restrict__ a_s, const float* __restrict__ a_d,
                            float* __restrict__ alpha, float* __restrict__ alpha_self)
{
    int d = blockIdx.x * 256 + threadIdx.x;
    if (d >= N_NODES) return;
    int base = offs[d], end = offs[d + 1];
    float4 ad = *(const float4*)(a_d + (size_t)d * 4);
    float4 asd = *(const float4*)(a_s + (size_t)d * 4);
    float es[4] = {lrelu(asd.x + ad.x), lrelu(asd.y + ad.y),
                   lrelu(asd.z + ad.z), lrelu(asd.w + ad.w)};
    float m[4] = {es[0], es[1], es[2], es[3]};
    for (int p = base; p < end; p++) {
        int s = csr[p];
        float4 as4 = *(const float4*)(a_s + (size_t)s * 4);
        m[0] = fmaxf(m[0], lrelu(as4.x + ad.x));
        m[1] = fmaxf(m[1], lrelu(as4.y + ad.y));
        m[2] = fmaxf(m[2], lrelu(as4.z + ad.z));
        m[3] = fmaxf(m[3], lrelu(as4.w + ad.w));
    }
    float den[4];
    #pragma unroll
    for (int h = 0; h < 4; h++) den[h] = expf(es[h] - m[h]);   // self term
    for (int p = base; p < end; p++) {
        int s = csr[p];
        float4 as4 = *(const float4*)(a_s + (size_t)s * 4);
        den[0] += expf(lrelu(as4.x + ad.x) - m[0]);
        den[1] += expf(lrelu(as4.y + ad.y) - m[1]);
        den[2] += expf(lrelu(as4.z + ad.z) - m[2]);
        den[3] += expf(lrelu(as4.w + ad.w) - m[3]);
    }
    float rden[4];
    #pragma unroll
    for (int h = 0; h < 4; h++) rden[h] = 1.0f / (den[h] + 1e-16f);
    for (int p = base; p < end; p++) {
        int s = csr[p];
        float4 as4 = *(const float4*)(a_s + (size_t)s * 4);
        float4 al;
        al.x = expf(lrelu(as4.x + ad.x) - m[0]) * rden[0];
        al.y = expf(lrelu(as4.y + ad.y) - m[1]) * rden[1];
        al.z = expf(lrelu(as4.z + ad.z) - m[2]) * rden[2];
        al.w = expf(lrelu(as4.w + ad.w) - m[3]) * rden[3];
        *(float4*)(alpha + (size_t)p * 4) = al;
    }
    float4 als;
    als.x = expf(es[0] - m[0]) * rden[0];
    als.y = expf(es[1] - m[1]) * rden[1];
    als.z = expf(es[2] - m[2]) * rden[2];
    als.w = expf(es[3] - m[3]) * rden[3];
    *(float4*)(alpha_self + (size_t)d * 4) = als;
}

// wave-per-node weighted gather (fused head-mean + bias + relu)
__global__ __launch_bounds__(256) void gat_gather(
    const int* __restrict__ offs, const int* __restrict__ csr,
    const float* __restrict__ alpha, const float* __restrict__ alpha_self,
    const float* __restrict__ xw, const float* __restrict__ ba,
    float* __restrict__ out)
{
    int lane = threadIdx.x & 63;
    int d = (blockIdx.x * 256 + threadIdx.x) >> 6;
    if (d >= N_NODES) return;
    int base = offs[d], end = offs[d + 1];
    int c2 = lane * 2;
    float2 acc = make_float2(0.f, 0.f);
    int i = base;
    while (i < end) {
        int chunk = min(64, end - i);
        int sv = 0;
        if (lane < chunk) sv = csr[i + lane];
        for (int j = 0; j < chunk; j++) {
            int s = __shfl(sv, j);
            float4 al = *(const float4*)(alpha + (size_t)(i + j) * 4);
            const float* row = xw + (size_t)s * 512 + c2;
            float2 v0 = *(const float2*)(row);
            float2 v1 = *(const float2*)(row + 128);
            float2 v2 = *(const float2*)(row + 256);
            float2 v3 = *(const float2*)(row + 384);
            acc.x = fmaf(v0.x, al.x, acc.x); acc.y = fmaf(v0.y, al.x, acc.y);
            acc.x = fmaf(v1.x, al.y, acc.x); acc.y = fmaf(v1.y, al.y, acc.y);
            acc.x = fmaf(v2.x, al.z, acc.x); acc.y = fmaf(v2.y, al.z, acc.y);
            acc.x = fmaf(v3.x, al.w, acc.x); acc.y = fmaf(v3.y, al.w, acc.y);
        }
        i += chunk;
    }
    float4 als = *(const float4*)(alpha_self + (size_t)d * 4);
    const float* row = xw + (size_t)d * 512 + c2;
    float2 v0 = *(const float2*)(row);
    float2 v1 = *(const float2*)(row + 128);
    float2 v2 = *(const float2*)(row + 256);
    float2 v3 = *(const float2*)(row + 384);
    acc.x = fmaf(v0.x, als.x, acc.x); acc.y = fmaf(v0.y, als.x, acc.y);
    acc.x = fmaf(v1.x, als.y, acc.x); acc.y = fmaf(v1.y, als.y, acc.y);
    acc.x = fmaf(v2.x, als.z, acc.x); acc.y = fmaf(v2.y, als.z, acc.y);
    acc.x = fmaf(v3.x, als.w, acc.x); acc.y = fmaf(v3.y, als.w, acc.y);
    float2 b2 = *(const float2*)(ba + c2);
    float2 o;
    o.x = fmaxf(0.25f * acc.x + b2.x, 0.f);
    o.y = fmaxf(0.25f * acc.y + b2.y, 0.f);
    *(float2*)(out + (size_t)d * HID + c2) = o;
}

// ---------- final heads (f32 output) ----------
__global__ void final_head(const float* __restrict__ sumvec,
                           const float* __restrict__ Wc1, const float* __restrict__ bc1,
                           const float* __restrict__ Wc2, const float* __restrict__ bc2,
                           const float* __restrict__ Wu, const float* __restrict__ bu,
                           float* __restrict__ out)
{
    __shared__ float xf[128];
    __shared__ float h1[64];
    int t = threadIdx.x;   // 128 threads
    xf[t] = sumvec[t] * (1.0f / N_NODES);
    __syncthreads();
    if (t < 64) {
        float s = bc1[t];
        for (int c = 0; c < 128; c++) s = fmaf(xf[c], Wc1[c * 64 + t], s);
        h1[t] = fmaxf(s, 0.f);
    }
    __syncthreads();
    if (t < 16) {
        float s = bc2[t];
        for (int j = 0; j < 64; j++) s = fmaf(h1[j], Wc2[j * 16 + t], s);
        out[t] = s;
        float u = bu[t];
        for (int c = 0; c < 128; c++) u = fmaf(xf[c], Wu[c * 16 + t], u);
        out[16 + t] = 1.0f / (1.0f + expf(-u));
    }
}

extern "C" void kernel_launch(void* const* d_in, const int* in_sizes, int n_in,
                              void* d_out, int out_size, void* d_ws, size_t ws_size,
                              hipStream_t stream) {
    const float* x    = (const float*)d_in[0];
    const int*   lei  = (const int*)d_in[1];
    const int*   gei  = (const int*)d_in[2];
    const float* W1   = (const float*)d_in[3];
    const float* b1   = (const float*)d_in[4];
    const float* Wg   = (const float*)d_in[5];
    const float* bg   = (const float*)d_in[6];
    const float* Wa   = (const float*)d_in[7];
    const float* atts = (const float*)d_in[8];
    const float* attd = (const float*)d_in[9];
    const float* ba   = (const float*)d_in[10];
    const float* Wp   = (const float*)d_in[11];
    const float* bp   = (const float*)d_in[12];
    const float* Wc1  = (const float*)d_in[13];
    const float* bc1  = (const float*)d_in[14];
    const float* Wc2  = (const float*)d_in[15];
    const float* bc2  = (const float*)d_in[16];
    const float* Wu   = (const float*)d_in[17];
    const float* bu   = (const float*)d_in[18];

    const int* lsrc = lei;
    const int* ldst = lei + EL;
    const int* gsrc = gei;
    const int* gdst = gei + EG;

    uintptr_t base = (uintptr_t)d_ws;
    auto alloc = [&](size_t bytes) { void* p = (void*)base; base += (bytes + 255) & ~(size_t)255; return p; };
    float* x_local   = (float*)alloc((size_t)N_NODES * HID * 4);
    float* x_lg      = (float*)alloc((size_t)N_NODES * HID * 4);
    float* x_gg      = (float*)alloc((size_t)N_NODES * HID * 4);
    float* big       = (float*)alloc((size_t)N_NODES * 512 * 4);   // xw_g then xw_a
    float* dinv      = (float*)alloc((size_t)N_NODES * 4);
    float* a_s       = (float*)alloc((size_t)N_NODES * 4 * 4);
    float* a_d       = (float*)alloc((size_t)N_NODES * 4 * 4);
    float* alpha_self= (float*)alloc((size_t)N_NODES * 4 * 4);
    int*   hist_l    = (int*)alloc((size_t)N_NODES * 4);
    int*   hist_g    = (int*)alloc((size_t)N_NODES * 4);
    int*   cur_l     = (int*)alloc((size_t)N_NODES * 4);
    int*   cur_g     = (int*)alloc((size_t)N_NODES * 4);
    int*   offs_l    = (int*)alloc(((size_t)N_NODES + 1) * 4);
    int*   offs_g    = (int*)alloc(((size_t)N_NODES + 1) * 4);
    int*   bsum      = (int*)alloc(256 * 4);
    int*   csr_l     = (int*)alloc((size_t)EL * 4);
    int*   csr_g     = (int*)alloc((size_t)EG * 4);
    float* alpha     = (float*)alloc((size_t)EG * 4 * 4);
    float* sumvec    = (float*)alloc(128 * 4);

    hipMemsetAsync(hist_l, 0, (size_t)N_NODES * 4, stream);
    hipMemsetAsync(hist_g, 0, (size_t)N_NODES * 4, stream);
    hipMemsetAsync(cur_l, 0, (size_t)N_NODES * 4, stream);
    hipMemsetAsync(cur_g, 0, (size_t)N_NODES * 4, stream);
    hipMemsetAsync(sumvec, 0, 128 * 4, stream);

    const int NB = 196;   // ceil(50000/256)

    // x_local = relu(x @ W1 + b1)
    gemm_f32<<<dim3(782, 2), 256, 0, stream>>>(x, W1, b1, x_local, N_NODES, 128, 128, 1);

    // ---- CSR build: local ----
    hist_kernel<<<3125, 256, 0, stream>>>(ldst, EL, hist_l);
    scan_partial<<<NB, 256, 0, stream>>>(hist_l, N_NODES, bsum);
    scan_bsums<<<1, 256, 0, stream>>>(bsum, NB);
    scan_final<<<NB, 256, 0, stream>>>(hist_l, N_NODES, bsum, offs_l, EL);
    fill_csr<<<3125, 256, 0, stream>>>(lsrc, ldst, EL, offs_l, cur_l, csr_l);
    dinv_from_offs<<<NB, 256, 0, stream>>>(offs_l, dinv);

    // ---- GCN branch ----
    gemm_f32<<<dim3(782, 2), 256, 0, stream>>>(x_local, Wg, nullptr, big, N_NODES, 128, 128, 0);
    gcn_gather<<<12500, 256, 0, stream>>>(offs_l, csr_l, big, dinv, bg, x_lg);

    // ---- CSR build: global ----
    hist_kernel<<<782, 256, 0, stream>>>(gdst, EG, hist_g);
    scan_partial<<<NB, 256, 0, stream>>>(hist_g, N_NODES, bsum);
    scan_bsums<<<1, 256, 0, stream>>>(bsum, NB);
    scan_final<<<NB, 256, 0, stream>>>(hist_g, N_NODES, bsum, offs_g, EG);
    fill_csr<<<782, 256, 0, stream>>>(gsrc, gdst, EG, offs_g, cur_g, csr_g);

    // ---- GAT branch ----
    gemm_f32<<<dim3(782, 8), 256, 0, stream>>>(x_local, Wa, nullptr, big, N_NODES, 128, 512, 0);
    attn_coef<<<12500, 256, 0, stream>>>(big, atts, attd, a_s, a_d);
    gat_softmax<<<NB, 256, 0, stream>>>(offs_g, csr_g, a_s, a_d, alpha, alpha_self);
    gat_gather<<<12500, 256, 0, stream>>>(offs_g, csr_g, alpha, alpha_self, big, ba, x_gg);

    // ---- pool + heads ----
    pooled_mean<<<dim3(782, 2), 256, 0, stream>>>(x_lg, x_gg, Wp, bp, sumvec);
    final_head<<<1, 128, 0, stream>>>(sumvec, Wc1, bc1, Wc2, bc2, Wu, bu,
                                      (float*)d_out);
}

// Round 5
// 359.367 us; speedup vs baseline: 3.5000x; 1.4842x over previous
//
#include <hip/hip_runtime.h>
#include <hip/hip_bf16.h>

#define N_NODES 50000
#define F_IN 128
#define HID 128
#define N_OUT 16
#define HEADS 4
#define EL 800000
#define EG 200000
#define NEG_SLOPE 0.2f

typedef short bf16x8 __attribute__((ext_vector_type(8)));
typedef float f32x4 __attribute__((ext_vector_type(4)));

static __device__ __forceinline__ float lrelu(float x) {
    return x > 0.f ? x : NEG_SLOPE * x;
}
static __device__ __forceinline__ unsigned short f2b(float f) {
    __hip_bfloat16 h = __float2bfloat16(f);
    return *reinterpret_cast<unsigned short*>(&h);
}
static __device__ __forceinline__ float b2f(unsigned u16) {
    return __uint_as_float((u16 & 0xffffu) << 16);
}

// ---------- converters ----------
__global__ void conv_bf16(const float* __restrict__ in, unsigned short* __restrict__ out, int n4) {
    int i = blockIdx.x * 256 + threadIdx.x;
    if (i >= n4) return;
    float4 v = *(const float4*)(in + 4 * (size_t)i);
    ushort4 o;
    o.x = f2b(v.x); o.y = f2b(v.y); o.z = f2b(v.z); o.w = f2b(v.w);
    *(ushort4*)(out + 4 * (size_t)i) = o;
}
// W[K][N] f32 -> Wt[N][K] bf16
__global__ void wtrans(const float* __restrict__ W, unsigned short* __restrict__ Wt, int K, int N) {
    int idx = blockIdx.x * 256 + threadIdx.x;
    if (idx >= K * N) return;
    int k = idx / N, n = idx % N;
    Wt[(size_t)n * K + k] = f2b(W[idx]);
}

// ---------- MFMA GEMM: out[M,N] = act(A[M,K] @ Bt[N,K]^T + bias), all bf16 in/out ----------
// 128x128 tile, 4 waves (2x2 of 64x64), K in {128,256} staged in 128-chunks.
__global__ __launch_bounds__(256) void mfma_gemm(
    const unsigned short* __restrict__ A, const unsigned short* __restrict__ Bt,
    const float* __restrict__ bias, unsigned short* __restrict__ out,
    int M, int K, int N, int relu_act)
{
    __shared__ unsigned short As[128 * 128];
    __shared__ unsigned short Bs[128 * 128];
    int tid = threadIdx.x;
    int lane = tid & 63, w = tid >> 6;
    int wr = w >> 1, wc = w & 1;
    int l16 = lane & 15, lhi = lane >> 4;
    int m0 = blockIdx.x * 128, n0 = blockIdx.y * 128;
    f32x4 acc[4][4] = {};
    for (int kb = 0; kb < K; kb += 128) {
        if (kb) __syncthreads();
        #pragma unroll
        for (int i = 0; i < 8; i++) {
            int u = tid + i * 256;                    // 0..2047
            int row = u >> 4, e0 = (u & 15) << 3;
            int sw = e0 ^ ((row & 7) << 3);
            bf16x8 va = {};
            int gr = m0 + row;
            if (gr < M) va = *(const bf16x8*)(A + (size_t)gr * K + kb + e0);
            *(bf16x8*)(As + row * 128 + sw) = va;
            int gn = n0 + row;
            bf16x8 vb = *(const bf16x8*)(Bt + (size_t)gn * K + kb + e0);
            *(bf16x8*)(Bs + row * 128 + sw) = vb;
        }
        __syncthreads();
        #pragma unroll
        for (int kk = 0; kk < 4; kk++) {
            int ke = kk * 32 + lhi * 8;
            bf16x8 af[4], bfr[4];
            #pragma unroll
            for (int m = 0; m < 4; m++) {
                int r = wr * 64 + m * 16 + l16;
                af[m] = *(const bf16x8*)(As + r * 128 + (ke ^ ((r & 7) << 3)));
            }
            #pragma unroll
            for (int n = 0; n < 4; n++) {
                int r = wc * 64 + n * 16 + l16;
                bfr[n] = *(const bf16x8*)(Bs + r * 128 + (ke ^ ((r & 7) << 3)));
            }
            #pragma unroll
            for (int m = 0; m < 4; m++)
                #pragma unroll
                for (int n = 0; n < 4; n++)
                    acc[m][n] = __builtin_amdgcn_mfma_f32_16x16x32_bf16(af[m], bfr[n], acc[m][n], 0, 0, 0);
        }
    }
    // epilogue: C[row][col], col = lane&15, row = (lane>>4)*4 + reg
    #pragma unroll
    for (int m = 0; m < 4; m++) {
        #pragma unroll
        for (int r = 0; r < 4; r++) {
            int row_g = m0 + wr * 64 + m * 16 + lhi * 4 + r;
            if (row_g >= M) continue;
            #pragma unroll
            for (int n = 0; n < 4; n++) {
                int col_g = n0 + wc * 64 + n * 16 + l16;
                float v = acc[m][n][r];
                if (bias) v += bias[col_g];
                if (relu_act) v = fmaxf(v, 0.f);
                out[(size_t)row_g * N + col_g] = f2b(v);
            }
        }
    }
}

// ---------- MFMA pooled GEMM + column-mean accumulation (K=256, N=128) ----------
__global__ __launch_bounds__(256) void mfma_pool(
    const unsigned short* __restrict__ A, const unsigned short* __restrict__ Bt,
    const float* __restrict__ bp, float* __restrict__ sumvec, int M)
{
    __shared__ unsigned short As[128 * 128];
    __shared__ unsigned short Bs[128 * 128];
    __shared__ float red[128];
    int tid = threadIdx.x;
    int lane = tid & 63, w = tid >> 6;
    int wr = w >> 1, wc = w & 1;
    int l16 = lane & 15, lhi = lane >> 4;
    int m0 = blockIdx.x * 128;
    f32x4 acc[4][4] = {};
    for (int kb = 0; kb < 256; kb += 128) {
        if (kb) __syncthreads();
        #pragma unroll
        for (int i = 0; i < 8; i++) {
            int u = tid + i * 256;
            int row = u >> 4, e0 = (u & 15) << 3;
            int sw = e0 ^ ((row & 7) << 3);
            bf16x8 va = {};
            int gr = m0 + row;
            if (gr < M) va = *(const bf16x8*)(A + (size_t)gr * 256 + kb + e0);
            *(bf16x8*)(As + row * 128 + sw) = va;
            bf16x8 vb = *(const bf16x8*)(Bt + (size_t)row * 256 + kb + e0);
            *(bf16x8*)(Bs + row * 128 + sw) = vb;
        }
        __syncthreads();
        #pragma unroll
        for (int kk = 0; kk < 4; kk++) {
            int ke = kk * 32 + lhi * 8;
            bf16x8 af[4], bfr[4];
            #pragma unroll
            for (int m = 0; m < 4; m++) {
                int r = wr * 64 + m * 16 + l16;
                af[m] = *(const bf16x8*)(As + r * 128 + (ke ^ ((r & 7) << 3)));
            }
            #pragma unroll
            for (int n = 0; n < 4; n++) {
                int r = wc * 64 + n * 16 + l16;
                bfr[n] = *(const bf16x8*)(Bs + r * 128 + (ke ^ ((r & 7) << 3)));
            }
            #pragma unroll
            for (int m = 0; m < 4; m++)
                #pragma unroll
                for (int n = 0; n < 4; n++)
                    acc[m][n] = __builtin_amdgcn_mfma_f32_16x16x32_bf16(af[m], bfr[n], acc[m][n], 0, 0, 0);
        }
    }
    float bcol[4];
    #pragma unroll
    for (int n = 0; n < 4; n++) bcol[n] = bp[wc * 64 + n * 16 + l16];
    float colsum[4] = {0.f, 0.f, 0.f, 0.f};
    #pragma unroll
    for (int m = 0; m < 4; m++) {
        #pragma unroll
        for (int r = 0; r < 4; r++) {
            int row_g = m0 + wr * 64 + m * 16 + lhi * 4 + r;
            if (row_g < M) {
                #pragma unroll
                for (int n = 0; n < 4; n++)
                    colsum[n] += fmaxf(acc[m][n][r] + bcol[n], 0.f);
            }
        }
    }
    #pragma unroll
    for (int n = 0; n < 4; n++) {
        colsum[n] += __shfl_xor(colsum[n], 16);
        colsum[n] += __shfl_xor(colsum[n], 32);
    }
    if (tid < 128) red[tid] = 0.f;
    __syncthreads();
    if (lhi == 0) {
        #pragma unroll
        for (int n = 0; n < 4; n++)
            atomicAdd(&red[wc * 64 + n * 16 + l16], colsum[n]);
    }
    __syncthreads();
    if (tid < 128) atomicAdd(&sumvec[tid], red[tid]);
}

// ---------- CSR build ----------
__global__ void hist_kernel(const int* __restrict__ dst, int nE, int* __restrict__ hist) {
    int e = blockIdx.x * 256 + threadIdx.x;
    if (e < nE) atomicAdd(&hist[dst[e]], 1);
}
__global__ void scan_partial(const int* __restrict__ hist, int n, int* __restrict__ bsum) {
    __shared__ int s[256];
    int i = blockIdx.x * 256 + threadIdx.x;
    s[threadIdx.x] = (i < n) ? hist[i] : 0;
    __syncthreads();
    for (int off = 128; off > 0; off >>= 1) {
        if (threadIdx.x < off) s[threadIdx.x] += s[threadIdx.x + off];
        __syncthreads();
    }
    if (threadIdx.x == 0) bsum[blockIdx.x] = s[0];
}
__global__ void scan_bsums(int* __restrict__ bsum, int nb) {
    __shared__ int s[256];
    int t = threadIdx.x;
    s[t] = (t < nb) ? bsum[t] : 0;
    __syncthreads();
    for (int off = 1; off < 256; off <<= 1) {
        int v = (t >= off) ? s[t - off] : 0;
        __syncthreads();
        s[t] += v;
        __syncthreads();
    }
    if (t < nb) bsum[t] = (t == 0) ? 0 : s[t - 1];
}
__global__ void scan_final(const int* __restrict__ hist, int n,
                           const int* __restrict__ bsum, int* __restrict__ offs, int total) {
    __shared__ int s[256];
    int t = threadIdx.x, i = blockIdx.x * 256 + t;
    int v = (i < n) ? hist[i] : 0;
    s[t] = v;
    __syncthreads();
    for (int off = 1; off < 256; off <<= 1) {
        int u = (t >= off) ? s[t - off] : 0;
        __syncthreads();
        s[t] += u;
        __syncthreads();
    }
    if (i < n) offs[i] = bsum[blockIdx.x] + s[t] - v;
    if (i == n - 1) offs[n] = total;
}
__global__ void fill_csr(const int* __restrict__ src, const int* __restrict__ dst, int nE,
                         const int* __restrict__ offs, int* __restrict__ cursor,
                         int* __restrict__ csr) {
    int e = blockIdx.x * 256 + threadIdx.x;
    if (e >= nE) return;
    int d = dst[e];
    int r = atomicAdd(&cursor[d], 1);
    csr[offs[d] + r] = src[e];
}
__global__ void dinv_from_offs(const int* __restrict__ offs, float* __restrict__ dinv) {
    int i = blockIdx.x * 256 + threadIdx.x;
    if (i < N_NODES) dinv[i] = rsqrtf((float)(offs[i + 1] - offs[i] + 1));
}

// ---------- GCN gather (bf16 xw, fused norm + self loop + bias + relu -> bf16 x_comb) ----------
__global__ __launch_bounds__(256) void gcn_gather(
    const int* __restrict__ offs, const int* __restrict__ csr,
    const unsigned short* __restrict__ xw, const float* __restrict__ dinv,
    const float* __restrict__ bg, unsigned short* __restrict__ xcomb)
{
    int lane = threadIdx.x & 63;
    int d = (blockIdx.x * 256 + threadIdx.x) >> 6;
    if (d >= N_NODES) return;
    int base = offs[d], end = offs[d + 1];
    int c2 = lane * 2;
    float ax = 0.f, ay = 0.f;
    for (int i = base; i < end; ) {
        int chunk = min(64, end - i);
        int sv = 0; float dvv = 0.f;
        if (lane < chunk) { sv = csr[i + lane]; dvv = dinv[sv]; }
        for (int j = 0; j < chunk; j++) {
            int s = __shfl(sv, j);
            float dv = __shfl(dvv, j);
            unsigned u = *(const unsigned*)(xw + (size_t)s * 128 + c2);
            ax = fmaf(b2f(u), dv, ax);
            ay = fmaf(b2f(u >> 16), dv, ay);
        }
        i += chunk;
    }
    float dd = dinv[d];
    unsigned us = *(const unsigned*)(xw + (size_t)d * 128 + c2);
    float ox = fmaxf(dd * ax + dd * dd * b2f(us) + bg[c2], 0.f);
    float oy = fmaxf(dd * ay + dd * dd * b2f(us >> 16) + bg[c2 + 1], 0.f);
    unsigned uo = (unsigned)f2b(ox) | ((unsigned)f2b(oy) << 16);
    *(unsigned*)(xcomb + (size_t)d * 256 + c2) = uo;
}

// ---------- GAT ----------
__global__ __launch_bounds__(256) void attn_coef(
    const unsigned short* __restrict__ xw, const float* __restrict__ atts,
    const float* __restrict__ attd, float* __restrict__ a_s, float* __restrict__ a_d)
{
    int lane = threadIdx.x & 63;
    int wid = (blockIdx.x * 256 + threadIdx.x) >> 6;
    float s8[8], d8[8];
    #pragma unroll
    for (int j = 0; j < 8; j++) { s8[j] = atts[lane * 8 + j]; d8[j] = attd[lane * 8 + j]; }
    if (wid >= N_NODES) return;
    uint4 u = *(const uint4*)(xw + (size_t)wid * 512 + lane * 8);
    float vv[8] = {b2f(u.x), b2f(u.x >> 16), b2f(u.y), b2f(u.y >> 16),
                   b2f(u.z), b2f(u.z >> 16), b2f(u.w), b2f(u.w >> 16)};
    float ps = 0.f, pd = 0.f;
    #pragma unroll
    for (int j = 0; j < 8; j++) { ps = fmaf(vv[j], s8[j], ps); pd = fmaf(vv[j], d8[j], pd); }
    #pragma unroll
    for (int off = 1; off < 16; off <<= 1) { ps += __shfl_xor(ps, off); pd += __shfl_xor(pd, off); }
    if ((lane & 15) == 0) {
        int h = lane >> 4;
        a_s[wid * 4 + h] = ps;
        a_d[wid * 4 + h] = pd;
    }
}

__global__ void gat_softmax(const int* __restrict__ offs, const int* __restrict__ csr,
                            const float* __restrict__ a_s, const float* __restrict__ a_d,
                            float* __restrict__ alpha, float* __restrict__ alpha_self)
{
    int d = blockIdx.x * 256 + threadIdx.x;
    if (d >= N_NODES) return;
    int base = offs[d], end = offs[d + 1];
    float4 ad = *(const float4*)(a_d + (size_t)d * 4);
    float4 asd = *(const float4*)(a_s + (size_t)d * 4);
    float es[4] = {lrelu(asd.x + ad.x), lrelu(asd.y + ad.y),
                   lrelu(asd.z + ad.z), lrelu(asd.w + ad.w)};
    float m[4] = {es[0], es[1], es[2], es[3]};
    for (int p = base; p < end; p++) {
        int s = csr[p];
        float4 as4 = *(const float4*)(a_s + (size_t)s * 4);
        m[0] = fmaxf(m[0], lrelu(as4.x + ad.x));
        m[1] = fmaxf(m[1], lrelu(as4.y + ad.y));
        m[2] = fmaxf(m[2], lrelu(as4.z + ad.z));
        m[3] = fmaxf(m[3], lrelu(as4.w + ad.w));
    }
    float den[4];
    #pragma unroll
    for (int h = 0; h < 4; h++) den[h] = expf(es[h] - m[h]);
    for (int p = base; p < end; p++) {
        int s = csr[p];
        float4 as4 = *(const float4*)(a_s + (size_t)s * 4);
        den[0] += expf(lrelu(as4.x + ad.x) - m[0]);
        den[1] += expf(lrelu(as4.y + ad.y) - m[1]);
        den[2] += expf(lrelu(as4.z + ad.z) - m[2]);
        den[3] += expf(lrelu(as4.w + ad.w) - m[3]);
    }
    float rden[4];
    #pragma unroll
    for (int h = 0; h < 4; h++) rden[h] = 1.0f / (den[h] + 1e-16f);
    for (int p = base; p < end; p++) {
        int s = csr[p];
        float4 as4 = *(const float4*)(a_s + (size_t)s * 4);
        float4 al;
        al.x = expf(lrelu(as4.x + ad.x) - m[0]) * rden[0];
        al.y = expf(lrelu(as4.y + ad.y) - m[1]) * rden[1];
        al.z = expf(lrelu(as4.z + ad.z) - m[2]) * rden[2];
        al.w = expf(lrelu(as4.w + ad.w) - m[3]) * rden[3];
        *(float4*)(alpha + (size_t)p * 4) = al;
    }
    float4 als;
    als.x = expf(es[0] - m[0]) * rden[0];
    als.y = expf(es[1] - m[1]) * rden[1];
    als.z = expf(es[2] - m[2]) * rden[2];
    als.w = expf(es[3] - m[3]) * rden[3];
    *(float4*)(alpha_self + (size_t)d * 4) = als;
}

// wave-per-node weighted gather (bf16 xw, fused head-mean + bias + relu -> bf16 x_comb)
__global__ __launch_bounds__(256) void gat_gather(
    const int* __restrict__ offs, const int* __restrict__ csr,
    const float* __restrict__ alpha, const float* __restrict__ alpha_self,
    const unsigned short* __restrict__ xw, const float* __restrict__ ba,
    unsigned short* __restrict__ xcomb)
{
    int lane = threadIdx.x & 63;
    int d = (blockIdx.x * 256 + threadIdx.x) >> 6;
    if (d >= N_NODES) return;
    int base = offs[d], end = offs[d + 1];
    int c2 = lane * 2;
    float ax = 0.f, ay = 0.f;
    for (int i = base; i < end; ) {
        int chunk = min(64, end - i);
        int sv = 0;
        if (lane < chunk) sv = csr[i + lane];
        for (int j = 0; j < chunk; j++) {
            int s = __shfl(sv, j);
            float4 al = *(const float4*)(alpha + (size_t)(i + j) * 4);
            const unsigned short* row = xw + (size_t)s * 512 + c2;
            unsigned u0 = *(const unsigned*)(row);
            unsigned u1 = *(const unsigned*)(row + 128);
            unsigned u2 = *(const unsigned*)(row + 256);
            unsigned u3 = *(const unsigned*)(row + 384);
            ax = fmaf(b2f(u0), al.x, ax); ay = fmaf(b2f(u0 >> 16), al.x, ay);
            ax = fmaf(b2f(u1), al.y, ax); ay = fmaf(b2f(u1 >> 16), al.y, ay);
            ax = fmaf(b2f(u2), al.z, ax); ay = fmaf(b2f(u2 >> 16), al.z, ay);
            ax = fmaf(b2f(u3), al.w, ax); ay = fmaf(b2f(u3 >> 16), al.w, ay);
        }
        i += chunk;
    }
    float4 als = *(const float4*)(alpha_self + (size_t)d * 4);
    const unsigned short* row = xw + (size_t)d * 512 + c2;
    unsigned u0 = *(const unsigned*)(row);
    unsigned u1 = *(const unsigned*)(row + 128);
    unsigned u2 = *(const unsigned*)(row + 256);
    unsigned u3 = *(const unsigned*)(row + 384);
    ax = fmaf(b2f(u0), als.x, ax); ay = fmaf(b2f(u0 >> 16), als.x, ay);
    ax = fmaf(b2f(u1), als.y, ax); ay = fmaf(b2f(u1 >> 16), als.y, ay);
    ax = fmaf(b2f(u2), als.z, ax); ay = fmaf(b2f(u2 >> 16), als.z, ay);
    ax = fmaf(b2f(u3), als.w, ax); ay = fmaf(b2f(u3 >> 16), als.w, ay);
    float ox = fmaxf(0.25f * ax + ba[c2], 0.f);
    float oy = fmaxf(0.25f * ay + ba[c2 + 1], 0.f);
    unsigned uo = (unsigned)f2b(ox) | ((unsigned)f2b(oy) << 16);
    *(unsigned*)(xcomb + (size_t)d * 256 + 128 + c2) = uo;
}

// ---------- final heads (f32 output) ----------
__global__ void final_head(const float* __restrict__ sumvec,
                           const float* __restrict__ Wc1, const float* __restrict__ bc1,
                           const float* __restrict__ Wc2, const float* __restrict__ bc2,
                           const float* __restrict__ Wu, const float* __restrict__ bu,
                           float* __restrict__ out)
{
    __shared__ float xf[128];
    __shared__ float h1[64];
    int t = threadIdx.x;   // 128 threads
    xf[t] = sumvec[t] * (1.0f / N_NODES);
    __syncthreads();
    if (t < 64) {
        float s = bc1[t];
        for (int c = 0; c < 128; c++) s = fmaf(xf[c], Wc1[c * 64 + t], s);
        h1[t] = fmaxf(s, 0.f);
    }
    __syncthreads();
    if (t < 16) {
        float s = bc2[t];
        for (int j = 0; j < 64; j++) s = fmaf(h1[j], Wc2[j * 16 + t], s);
        out[t] = s;
        float u = bu[t];
        for (int c = 0; c < 128; c++) u = fmaf(xf[c], Wu[c * 16 + t], u);
        out[16 + t] = 1.0f / (1.0f + expf(-u));
    }
}

extern "C" void kernel_launch(void* const* d_in, const int* in_sizes, int n_in,
                              void* d_out, int out_size, void* d_ws, size_t ws_size,
                              hipStream_t stream) {
    const float* x    = (const float*)d_in[0];
    const int*   lei  = (const int*)d_in[1];
    const int*   gei  = (const int*)d_in[2];
    const float* W1   = (const float*)d_in[3];
    const float* b1   = (const float*)d_in[4];
    const float* Wg   = (const float*)d_in[5];
    const float* bg   = (const float*)d_in[6];
    const float* Wa   = (const float*)d_in[7];
    const float* atts = (const float*)d_in[8];
    const float* attd = (const float*)d_in[9];
    const float* ba   = (const float*)d_in[10];
    const float* Wp   = (const float*)d_in[11];
    const float* bp   = (const float*)d_in[12];
    const float* Wc1  = (const float*)d_in[13];
    const float* bc1  = (const float*)d_in[14];
    const float* Wc2  = (const float*)d_in[15];
    const float* bc2  = (const float*)d_in[16];
    const float* Wu   = (const float*)d_in[17];
    const float* bu   = (const float*)d_in[18];

    const int* lsrc = lei;
    const int* ldst = lei + EL;
    const int* gsrc = gei;
    const int* gdst = gei + EG;

    uintptr_t base = (uintptr_t)d_ws;
    auto alloc = [&](size_t bytes) { void* p = (void*)base; base += (bytes + 255) & ~(size_t)255; return p; };
    unsigned short* xb     = (unsigned short*)alloc((size_t)N_NODES * 128 * 2);
    unsigned short* x_loc  = (unsigned short*)alloc((size_t)N_NODES * 128 * 2);
    unsigned short* xw_g   = (unsigned short*)alloc((size_t)N_NODES * 128 * 2);
    unsigned short* xw_a   = (unsigned short*)alloc((size_t)N_NODES * 512 * 2);
    unsigned short* xcomb  = (unsigned short*)alloc((size_t)N_NODES * 256 * 2);
    unsigned short* W1t    = (unsigned short*)alloc((size_t)128 * 128 * 2);
    unsigned short* Wgt    = (unsigned short*)alloc((size_t)128 * 128 * 2);
    unsigned short* Wat    = (unsigned short*)alloc((size_t)512 * 128 * 2);
    unsigned short* Wpt    = (unsigned short*)alloc((size_t)128 * 256 * 2);
    float* dinv       = (float*)alloc((size_t)N_NODES * 4);
    float* a_s        = (float*)alloc((size_t)N_NODES * 4 * 4);
    float* a_d        = (float*)alloc((size_t)N_NODES * 4 * 4);
    float* alpha_self = (float*)alloc((size_t)N_NODES * 4 * 4);
    int*   hist_l     = (int*)alloc((size_t)N_NODES * 4);
    int*   hist_g     = (int*)alloc((size_t)N_NODES * 4);
    int*   cur_l      = (int*)alloc((size_t)N_NODES * 4);
    int*   cur_g      = (int*)alloc((size_t)N_NODES * 4);
    int*   offs_l     = (int*)alloc(((size_t)N_NODES + 1) * 4);
    int*   offs_g     = (int*)alloc(((size_t)N_NODES + 1) * 4);
    int*   bsum       = (int*)alloc(256 * 4);
    int*   csr_l      = (int*)alloc((size_t)EL * 4);
    int*   csr_g      = (int*)alloc((size_t)EG * 4);
    float* alpha      = (float*)alloc((size_t)EG * 4 * 4);
    float* sumvec     = (float*)alloc(128 * 4);

    hipMemsetAsync(hist_l, 0, (size_t)N_NODES * 4, stream);
    hipMemsetAsync(hist_g, 0, (size_t)N_NODES * 4, stream);
    hipMemsetAsync(cur_l, 0, (size_t)N_NODES * 4, stream);
    hipMemsetAsync(cur_g, 0, (size_t)N_NODES * 4, stream);
    hipMemsetAsync(sumvec, 0, 128 * 4, stream);

    const int NB = 196;      // ceil(50000/256)
    const int GB = 391;      // ceil(50000/128)

    // converters
    conv_bf16<<<6250, 256, 0, stream>>>(x, xb, N_NODES * 128 / 4);
    wtrans<<<64, 256, 0, stream>>>(W1, W1t, 128, 128);
    wtrans<<<64, 256, 0, stream>>>(Wg, Wgt, 128, 128);
    wtrans<<<256, 256, 0, stream>>>(Wa, Wat, 128, 512);
    wtrans<<<128, 256, 0, stream>>>(Wp, Wpt, 256, 128);

    // x_local = relu(x @ W1 + b1)
    mfma_gemm<<<dim3(GB, 1), 256, 0, stream>>>(xb, W1t, b1, x_loc, N_NODES, 128, 128, 1);

    // ---- CSR build: local ----
    hist_kernel<<<3125, 256, 0, stream>>>(ldst, EL, hist_l);
    scan_partial<<<NB, 256, 0, stream>>>(hist_l, N_NODES, bsum);
    scan_bsums<<<1, 256, 0, stream>>>(bsum, NB);
    scan_final<<<NB, 256, 0, stream>>>(hist_l, N_NODES, bsum, offs_l, EL);
    fill_csr<<<3125, 256, 0, stream>>>(lsrc, ldst, EL, offs_l, cur_l, csr_l);
    dinv_from_offs<<<NB, 256, 0, stream>>>(offs_l, dinv);

    // ---- GCN branch ----
    mfma_gemm<<<dim3(GB, 1), 256, 0, stream>>>(x_loc, Wgt, nullptr, xw_g, N_NODES, 128, 128, 0);
    gcn_gather<<<12500, 256, 0, stream>>>(offs_l, csr_l, xw_g, dinv, bg, xcomb);

    // ---- CSR build: global ----
    hist_kernel<<<782, 256, 0, stream>>>(gdst, EG, hist_g);
    scan_partial<<<NB, 256, 0, stream>>>(hist_g, N_NODES, bsum);
    scan_bsums<<<1, 256, 0, stream>>>(bsum, NB);
    scan_final<<<NB, 256, 0, stream>>>(hist_g, N_NODES, bsum, offs_g, EG);
    fill_csr<<<782, 256, 0, stream>>>(gsrc, gdst, EG, offs_g, cur_g, csr_g);

    // ---- GAT branch ----
    mfma_gemm<<<dim3(GB, 4), 256, 0, stream>>>(x_loc, Wat, nullptr, xw_a, N_NODES, 128, 512, 0);
    attn_coef<<<12500, 256, 0, stream>>>(xw_a, atts, attd, a_s, a_d);
    gat_softmax<<<NB, 256, 0, stream>>>(offs_g, csr_g, a_s, a_d, alpha, alpha_self);
    gat_gather<<<12500, 256, 0, stream>>>(offs_g, csr_g, alpha, alpha_self, xw_a, ba, xcomb);

    // ---- pool + heads ----
    mfma_pool<<<dim3(GB, 1), 256, 0, stream>>>(xcomb, Wpt, bp, sumvec, N_NODES);
    final_head<<<1, 128, 0, stream>>>(sumvec, Wc1, bc1, Wc2, bc2, Wu, bu,
                                      (float*)d_out);
}

// Round 6
// 320.256 us; speedup vs baseline: 3.9274x; 1.1221x over previous
//
#include <hip/hip_runtime.h>
#include <hip/hip_bf16.h>

#define N_NODES 50000
#define F_IN 128
#define HID 128
#define N_OUT 16
#define HEADS 4
#define EL 800000
#define EG 200000
#define NEG_SLOPE 0.2f
#define NB 196   // ceil(50000/256)
#define GB 391   // ceil(50000/128)

typedef short bf16x8 __attribute__((ext_vector_type(8)));
typedef float f32x4 __attribute__((ext_vector_type(4)));

static __device__ __forceinline__ float lrelu(float x) {
    return x > 0.f ? x : NEG_SLOPE * x;
}
static __device__ __forceinline__ unsigned short f2b(float f) {
    __hip_bfloat16 h = __float2bfloat16(f);
    return *reinterpret_cast<unsigned short*>(&h);
}
static __device__ __forceinline__ float b2f(unsigned u16) {
    return __uint_as_float((u16 & 0xffffu) << 16);
}

// ---------- fused converters: x -> bf16, 4 weights -> transposed bf16 ----------
__global__ void conv_all(const float* __restrict__ x, unsigned short* __restrict__ xb,
                         const float* __restrict__ W1, unsigned short* __restrict__ W1t,
                         const float* __restrict__ Wg, unsigned short* __restrict__ Wgt,
                         const float* __restrict__ Wa, unsigned short* __restrict__ Wat,
                         const float* __restrict__ Wp, unsigned short* __restrict__ Wpt)
{
    int b = blockIdx.x, t = threadIdx.x;
    if (b < 6250) {                       // x: 1.6M float4 groups /4 = 400k? -> elems = N*128/4 = 1.6M vec4
        int i = b * 256 + t;
        float4 v = *(const float4*)(x + 4 * (size_t)i);
        ushort4 o;
        o.x = f2b(v.x); o.y = f2b(v.y); o.z = f2b(v.z); o.w = f2b(v.w);
        *(ushort4*)(xb + 4 * (size_t)i) = o;
    } else if (b < 6314) {                // W1 [128][128]
        int idx = (b - 6250) * 256 + t;
        int k = idx >> 7, n = idx & 127;
        W1t[n * 128 + k] = f2b(W1[idx]);
    } else if (b < 6378) {                // Wg [128][128]
        int idx = (b - 6314) * 256 + t;
        int k = idx >> 7, n = idx & 127;
        Wgt[n * 128 + k] = f2b(Wg[idx]);
    } else if (b < 6634) {                // Wa [128][512]
        int idx = (b - 6378) * 256 + t;
        int k = idx >> 9, n = idx & 511;
        Wat[(size_t)n * 128 + k] = f2b(Wa[idx]);
    } else {                              // Wp [256][128]
        int idx = (b - 6634) * 256 + t;
        int k = idx >> 7, n = idx & 127;
        Wpt[(size_t)n * 256 + k] = f2b(Wp[idx]);
    }
}

// ---------- MFMA GEMM: out[M,N] = act(A[M,K] @ Bt[N,K]^T + bias), bf16 in/out ----------
__global__ __launch_bounds__(256) void mfma_gemm(
    const unsigned short* __restrict__ A, const unsigned short* __restrict__ Bt,
    const float* __restrict__ bias, unsigned short* __restrict__ out,
    int M, int K, int N, int relu_act)
{
    __shared__ unsigned short As[128 * 128];
    __shared__ unsigned short Bs[128 * 128];
    int tid = threadIdx.x;
    int lane = tid & 63, w = tid >> 6;
    int wr = w >> 1, wc = w & 1;
    int l16 = lane & 15, lhi = lane >> 4;
    int m0 = blockIdx.x * 128, n0 = blockIdx.y * 128;
    f32x4 acc[4][4] = {};
    for (int kb = 0; kb < K; kb += 128) {
        if (kb) __syncthreads();
        #pragma unroll
        for (int i = 0; i < 8; i++) {
            int u = tid + i * 256;
            int row = u >> 4, e0 = (u & 15) << 3;
            int sw = e0 ^ ((row & 7) << 3);
            bf16x8 va = {};
            int gr = m0 + row;
            if (gr < M) va = *(const bf16x8*)(A + (size_t)gr * K + kb + e0);
            *(bf16x8*)(As + row * 128 + sw) = va;
            int gn = n0 + row;
            bf16x8 vb = *(const bf16x8*)(Bt + (size_t)gn * K + kb + e0);
            *(bf16x8*)(Bs + row * 128 + sw) = vb;
        }
        __syncthreads();
        #pragma unroll
        for (int kk = 0; kk < 4; kk++) {
            int ke = kk * 32 + lhi * 8;
            bf16x8 af[4], bfr[4];
            #pragma unroll
            for (int m = 0; m < 4; m++) {
                int r = wr * 64 + m * 16 + l16;
                af[m] = *(const bf16x8*)(As + r * 128 + (ke ^ ((r & 7) << 3)));
            }
            #pragma unroll
            for (int n = 0; n < 4; n++) {
                int r = wc * 64 + n * 16 + l16;
                bfr[n] = *(const bf16x8*)(Bs + r * 128 + (ke ^ ((r & 7) << 3)));
            }
            #pragma unroll
            for (int m = 0; m < 4; m++)
                #pragma unroll
                for (int n = 0; n < 4; n++)
                    acc[m][n] = __builtin_amdgcn_mfma_f32_16x16x32_bf16(af[m], bfr[n], acc[m][n], 0, 0, 0);
        }
    }
    #pragma unroll
    for (int m = 0; m < 4; m++) {
        #pragma unroll
        for (int r = 0; r < 4; r++) {
            int row_g = m0 + wr * 64 + m * 16 + lhi * 4 + r;
            if (row_g >= M) continue;
            #pragma unroll
            for (int n = 0; n < 4; n++) {
                int col_g = n0 + wc * 64 + n * 16 + l16;
                float v = acc[m][n][r];
                if (bias) v += bias[col_g];
                if (relu_act) v = fmaxf(v, 0.f);
                out[(size_t)row_g * N + col_g] = f2b(v);
            }
        }
    }
}

// ---------- MFMA GEMM for Wa with fused attention-coefficient epilogue ----------
// grid (GB, 4): blockIdx.y == head; cols n0..n0+127 are exactly head's channels.
__global__ __launch_bounds__(256) void mfma_gemm_attn(
    const unsigned short* __restrict__ A, const unsigned short* __restrict__ Bt,
    unsigned short* __restrict__ out, int M,
    const float* __restrict__ atts, const float* __restrict__ attd,
    float* __restrict__ a_s, float* __restrict__ a_d)
{
    __shared__ unsigned short As[128 * 128];
    __shared__ unsigned short Bs[128 * 128];
    __shared__ float sas[128], sad[128];
    int tid = threadIdx.x;
    int lane = tid & 63, w = tid >> 6;
    int wr = w >> 1, wc = w & 1;
    int l16 = lane & 15, lhi = lane >> 4;
    int m0 = blockIdx.x * 128, n0 = blockIdx.y * 128;
    int head = blockIdx.y;
    f32x4 acc[4][4] = {};
    {
        #pragma unroll
        for (int i = 0; i < 8; i++) {
            int u = tid + i * 256;
            int row = u >> 4, e0 = (u & 15) << 3;
            int sw = e0 ^ ((row & 7) << 3);
            bf16x8 va = {};
            int gr = m0 + row;
            if (gr < M) va = *(const bf16x8*)(A + (size_t)gr * 128 + e0);
            *(bf16x8*)(As + row * 128 + sw) = va;
            int gn = n0 + row;
            bf16x8 vb = *(const bf16x8*)(Bt + (size_t)gn * 128 + e0);
            *(bf16x8*)(Bs + row * 128 + sw) = vb;
        }
        if (tid < 128) { sas[tid] = 0.f; sad[tid] = 0.f; }
        __syncthreads();
        #pragma unroll
        for (int kk = 0; kk < 4; kk++) {
            int ke = kk * 32 + lhi * 8;
            bf16x8 af[4], bfr[4];
            #pragma unroll
            for (int m = 0; m < 4; m++) {
                int r = wr * 64 + m * 16 + l16;
                af[m] = *(const bf16x8*)(As + r * 128 + (ke ^ ((r & 7) << 3)));
            }
            #pragma unroll
            for (int n = 0; n < 4; n++) {
                int r = wc * 64 + n * 16 + l16;
                bfr[n] = *(const bf16x8*)(Bs + r * 128 + (ke ^ ((r & 7) << 3)));
            }
            #pragma unroll
            for (int m = 0; m < 4; m++)
                #pragma unroll
                for (int n = 0; n < 4; n++)
                    acc[m][n] = __builtin_amdgcn_mfma_f32_16x16x32_bf16(af[m], bfr[n], acc[m][n], 0, 0, 0);
        }
    }
    float ats[4], atd[4];
    #pragma unroll
    for (int n = 0; n < 4; n++) {
        int cl = wc * 64 + n * 16 + l16;
        ats[n] = atts[head * 128 + cl];
        atd[n] = attd[head * 128 + cl];
    }
    #pragma unroll
    for (int m = 0; m < 4; m++) {
        #pragma unroll
        for (int r = 0; r < 4; r++) {
            int row_l = wr * 64 + m * 16 + lhi * 4 + r;
            int row_g = m0 + row_l;
            float ps = 0.f, pd = 0.f;
            #pragma unroll
            for (int n = 0; n < 4; n++) {
                float v = acc[m][n][r];
                ps = fmaf(v, ats[n], ps);
                pd = fmaf(v, atd[n], pd);
                if (row_g < M) {
                    int col_g = n0 + wc * 64 + n * 16 + l16;
                    out[(size_t)row_g * 512 + col_g] = f2b(v);
                }
            }
            #pragma unroll
            for (int off = 1; off < 16; off <<= 1) {
                ps += __shfl_xor(ps, off);
                pd += __shfl_xor(pd, off);
            }
            if (l16 == 0) {
                atomicAdd(&sas[row_l], ps);
                atomicAdd(&sad[row_l], pd);
            }
        }
    }
    __syncthreads();
    if (tid < 128) {
        int row_g = m0 + tid;
        if (row_g < M) {
            a_s[(size_t)row_g * 4 + head] = sas[tid];
            a_d[(size_t)row_g * 4 + head] = sad[tid];
        }
    }
}

// ---------- MFMA pooled GEMM + column-mean accumulation (K=256, N=128) ----------
__global__ __launch_bounds__(256) void mfma_pool(
    const unsigned short* __restrict__ A, const unsigned short* __restrict__ Bt,
    const float* __restrict__ bp, float* __restrict__ sumvec, int M)
{
    __shared__ unsigned short As[128 * 128];
    __shared__ unsigned short Bs[128 * 128];
    __shared__ float red[128];
    int tid = threadIdx.x;
    int lane = tid & 63, w = tid >> 6;
    int wr = w >> 1, wc = w & 1;
    int l16 = lane & 15, lhi = lane >> 4;
    int m0 = blockIdx.x * 128;
    f32x4 acc[4][4] = {};
    for (int kb = 0; kb < 256; kb += 128) {
        if (kb) __syncthreads();
        #pragma unroll
        for (int i = 0; i < 8; i++) {
            int u = tid + i * 256;
            int row = u >> 4, e0 = (u & 15) << 3;
            int sw = e0 ^ ((row & 7) << 3);
            bf16x8 va = {};
            int gr = m0 + row;
            if (gr < M) va = *(const bf16x8*)(A + (size_t)gr * 256 + kb + e0);
            *(bf16x8*)(As + row * 128 + sw) = va;
            bf16x8 vb = *(const bf16x8*)(Bt + (size_t)row * 256 + kb + e0);
            *(bf16x8*)(Bs + row * 128 + sw) = vb;
        }
        __syncthreads();
        #pragma unroll
        for (int kk = 0; kk < 4; kk++) {
            int ke = kk * 32 + lhi * 8;
            bf16x8 af[4], bfr[4];
            #pragma unroll
            for (int m = 0; m < 4; m++) {
                int r = wr * 64 + m * 16 + l16;
                af[m] = *(const bf16x8*)(As + r * 128 + (ke ^ ((r & 7) << 3)));
            }
            #pragma unroll
            for (int n = 0; n < 4; n++) {
                int r = wc * 64 + n * 16 + l16;
                bfr[n] = *(const bf16x8*)(Bs + r * 128 + (ke ^ ((r & 7) << 3)));
            }
            #pragma unroll
            for (int m = 0; m < 4; m++)
                #pragma unroll
                for (int n = 0; n < 4; n++)
                    acc[m][n] = __builtin_amdgcn_mfma_f32_16x16x32_bf16(af[m], bfr[n], acc[m][n], 0, 0, 0);
        }
    }
    float bcol[4];
    #pragma unroll
    for (int n = 0; n < 4; n++) bcol[n] = bp[wc * 64 + n * 16 + l16];
    float colsum[4] = {0.f, 0.f, 0.f, 0.f};
    #pragma unroll
    for (int m = 0; m < 4; m++) {
        #pragma unroll
        for (int r = 0; r < 4; r++) {
            int row_g = m0 + wr * 64 + m * 16 + lhi * 4 + r;
            if (row_g < M) {
                #pragma unroll
                for (int n = 0; n < 4; n++)
                    colsum[n] += fmaxf(acc[m][n][r] + bcol[n], 0.f);
            }
        }
    }
    #pragma unroll
    for (int n = 0; n < 4; n++) {
        colsum[n] += __shfl_xor(colsum[n], 16);
        colsum[n] += __shfl_xor(colsum[n], 32);
    }
    if (tid < 128) red[tid] = 0.f;
    __syncthreads();
    if (lhi == 0) {
        #pragma unroll
        for (int n = 0; n < 4; n++)
            atomicAdd(&red[wc * 64 + n * 16 + l16], colsum[n]);
    }
    __syncthreads();
    if (tid < 128) atomicAdd(&sumvec[tid], red[tid]);
}

// ---------- CSR build (both graphs fused per stage) ----------
__global__ void hist_both(const int* __restrict__ ldst, const int* __restrict__ gdst,
                          int* __restrict__ hist_l, int* __restrict__ hist_g)
{
    int b = blockIdx.x;
    if (b < 3125) {
        int e = b * 256 + threadIdx.x;
        if (e < EL) atomicAdd(&hist_l[ldst[e]], 1);
    } else {
        int e = (b - 3125) * 256 + threadIdx.x;
        if (e < EG) atomicAdd(&hist_g[gdst[e]], 1);
    }
}
__global__ void scan_partial_both(const int* __restrict__ hist_l, const int* __restrict__ hist_g,
                                  int* __restrict__ bsum_l, int* __restrict__ bsum_g)
{
    __shared__ int s[256];
    int b = blockIdx.x;
    const int* hist = (b < NB) ? hist_l : hist_g;
    int* bsum = (b < NB) ? bsum_l : bsum_g;
    int blk = (b < NB) ? b : b - NB;
    int i = blk * 256 + threadIdx.x;
    s[threadIdx.x] = (i < N_NODES) ? hist[i] : 0;
    __syncthreads();
    for (int off = 128; off > 0; off >>= 1) {
        if (threadIdx.x < off) s[threadIdx.x] += s[threadIdx.x + off];
        __syncthreads();
    }
    if (threadIdx.x == 0) bsum[blk] = s[0];
}
__global__ void scan_bsums_both(int* __restrict__ bsum_l, int* __restrict__ bsum_g)
{
    __shared__ int s[256];
    int* bsum = (blockIdx.x == 0) ? bsum_l : bsum_g;
    int t = threadIdx.x;
    s[t] = (t < NB) ? bsum[t] : 0;
    __syncthreads();
    for (int off = 1; off < 256; off <<= 1) {
        int v = (t >= off) ? s[t - off] : 0;
        __syncthreads();
        s[t] += v;
        __syncthreads();
    }
    if (t < NB) bsum[t] = (t == 0) ? 0 : s[t - 1];
}
// exclusive offsets + cursor copy (+dinv for local graph)
__global__ void scan_final_both(const int* __restrict__ hist_l, const int* __restrict__ hist_g,
                                const int* __restrict__ bsum_l, const int* __restrict__ bsum_g,
                                int* __restrict__ offs_l, int* __restrict__ cur_l,
                                int* __restrict__ offs_g, int* __restrict__ cur_g,
                                float* __restrict__ dinv)
{
    __shared__ int s[256];
    int b = blockIdx.x;
    bool loc = (b < NB);
    int blk = loc ? b : b - NB;
    const int* hist = loc ? hist_l : hist_g;
    const int* bsum = loc ? bsum_l : bsum_g;
    int* offs = loc ? offs_l : offs_g;
    int* cur  = loc ? cur_l : cur_g;
    int t = threadIdx.x, i = blk * 256 + t;
    int v = (i < N_NODES) ? hist[i] : 0;
    s[t] = v;
    __syncthreads();
    for (int off = 1; off < 256; off <<= 1) {
        int u = (t >= off) ? s[t - off] : 0;
        __syncthreads();
        s[t] += u;
        __syncthreads();
    }
    if (i < N_NODES) {
        int o = bsum[blk] + s[t] - v;
        offs[i] = o;
        cur[i] = o;
        if (loc) dinv[i] = rsqrtf((float)(v + 1));
    }
    if (i == N_NODES - 1) offs[N_NODES] = loc ? EL : EG;
}
// cursor holds absolute positions; csr entries are ushort (ids < 65536)
__global__ void fill_both(const int* __restrict__ lsrc, const int* __restrict__ ldst,
                          const int* __restrict__ gsrc, const int* __restrict__ gdst,
                          int* __restrict__ cur_l, int* __restrict__ cur_g,
                          unsigned short* __restrict__ csr_l, unsigned short* __restrict__ csr_g)
{
    int b = blockIdx.x;
    if (b < 3125) {
        int e = b * 256 + threadIdx.x;
        if (e < EL) {
            int d = ldst[e];
            int r = atomicAdd(&cur_l[d], 1);
            csr_l[r] = (unsigned short)lsrc[e];
        }
    } else {
        int e = (b - 3125) * 256 + threadIdx.x;
        if (e < EG) {
            int d = gdst[e];
            int r = atomicAdd(&cur_g[d], 1);
            csr_g[r] = (unsigned short)gsrc[e];
        }
    }
}

// ---------- GCN gather, unroll 4 ----------
__global__ __launch_bounds__(256) void gcn_gather(
    const int* __restrict__ offs, const unsigned short* __restrict__ csr,
    const unsigned short* __restrict__ xw, const float* __restrict__ dinv,
    const float* __restrict__ bg, unsigned short* __restrict__ xcomb)
{
    int lane = threadIdx.x & 63;
    int d = (blockIdx.x * 256 + threadIdx.x) >> 6;
    if (d >= N_NODES) return;
    int base = offs[d], end = offs[d + 1];
    int c2 = lane * 2;
    float ax = 0.f, ay = 0.f;
    for (int i = base; i < end; ) {
        int chunk = min(64, end - i);
        int sv = 0; float dvv = 0.f;
        if (lane < chunk) { sv = csr[i + lane]; dvv = dinv[sv]; }
        int j = 0;
        for (; j + 4 <= chunk; j += 4) {
            int s0 = __shfl(sv, j),     s1 = __shfl(sv, j + 1);
            int s2 = __shfl(sv, j + 2), s3 = __shfl(sv, j + 3);
            float d0 = __shfl(dvv, j),     d1 = __shfl(dvv, j + 1);
            float d2 = __shfl(dvv, j + 2), d3 = __shfl(dvv, j + 3);
            unsigned u0 = *(const unsigned*)(xw + (size_t)s0 * 128 + c2);
            unsigned u1 = *(const unsigned*)(xw + (size_t)s1 * 128 + c2);
            unsigned u2 = *(const unsigned*)(xw + (size_t)s2 * 128 + c2);
            unsigned u3 = *(const unsigned*)(xw + (size_t)s3 * 128 + c2);
            ax = fmaf(b2f(u0), d0, ax); ay = fmaf(b2f(u0 >> 16), d0, ay);
            ax = fmaf(b2f(u1), d1, ax); ay = fmaf(b2f(u1 >> 16), d1, ay);
            ax = fmaf(b2f(u2), d2, ax); ay = fmaf(b2f(u2 >> 16), d2, ay);
            ax = fmaf(b2f(u3), d3, ax); ay = fmaf(b2f(u3 >> 16), d3, ay);
        }
        for (; j < chunk; j++) {
            int s = __shfl(sv, j);
            float dv = __shfl(dvv, j);
            unsigned u = *(const unsigned*)(xw + (size_t)s * 128 + c2);
            ax = fmaf(b2f(u), dv, ax);
            ay = fmaf(b2f(u >> 16), dv, ay);
        }
        i += chunk;
    }
    float dd = dinv[d];
    unsigned us = *(const unsigned*)(xw + (size_t)d * 128 + c2);
    float ox = fmaxf(dd * ax + dd * dd * b2f(us) + bg[c2], 0.f);
    float oy = fmaxf(dd * ay + dd * dd * b2f(us >> 16) + bg[c2 + 1], 0.f);
    unsigned uo = (unsigned)f2b(ox) | ((unsigned)f2b(oy) << 16);
    *(unsigned*)(xcomb + (size_t)d * 256 + c2) = uo;
}

// ---------- GAT ----------
__global__ void gat_softmax(const int* __restrict__ offs, const unsigned short* __restrict__ csr,
                            const float* __restrict__ a_s, const float* __restrict__ a_d,
                            float* __restrict__ alpha, float* __restrict__ alpha_self)
{
    int d = blockIdx.x * 256 + threadIdx.x;
    if (d >= N_NODES) return;
    int base = offs[d], end = offs[d + 1];
    float4 ad = *(const float4*)(a_d + (size_t)d * 4);
    float4 asd = *(const float4*)(a_s + (size_t)d * 4);
    float es[4] = {lrelu(asd.x + ad.x), lrelu(asd.y + ad.y),
                   lrelu(asd.z + ad.z), lrelu(asd.w + ad.w)};
    float m[4] = {es[0], es[1], es[2], es[3]};
    for (int p = base; p < end; p++) {
        int s = csr[p];
        float4 as4 = *(const float4*)(a_s + (size_t)s * 4);
        m[0] = fmaxf(m[0], lrelu(as4.x + ad.x));
        m[1] = fmaxf(m[1], lrelu(as4.y + ad.y));
        m[2] = fmaxf(m[2], lrelu(as4.z + ad.z));
        m[3] = fmaxf(m[3], lrelu(as4.w + ad.w));
    }
    float den[4];
    #pragma unroll
    for (int h = 0; h < 4; h++) den[h] = expf(es[h] - m[h]);
    for (int p = base; p < end; p++) {
        int s = csr[p];
        float4 as4 = *(const float4*)(a_s + (size_t)s * 4);
        den[0] += expf(lrelu(as4.x + ad.x) - m[0]);
        den[1] += expf(lrelu(as4.y + ad.y) - m[1]);
        den[2] += expf(lrelu(as4.z + ad.z) - m[2]);
        den[3] += expf(lrelu(as4.w + ad.w) - m[3]);
    }
    float rden[4];
    #pragma unroll
    for (int h = 0; h < 4; h++) rden[h] = 1.0f / (den[h] + 1e-16f);
    for (int p = base; p < end; p++) {
        int s = csr[p];
        float4 as4 = *(const float4*)(a_s + (size_t)s * 4);
        float4 al;
        al.x = expf(lrelu(as4.x + ad.x) - m[0]) * rden[0];
        al.y = expf(lrelu(as4.y + ad.y) - m[1]) * rden[1];
        al.z = expf(lrelu(as4.z + ad.z) - m[2]) * rden[2];
        al.w = expf(lrelu(as4.w + ad.w) - m[3]) * rden[3];
        *(float4*)(alpha + (size_t)p * 4) = al;
    }
    float4 als;
    als.x = expf(es[0] - m[0]) * rden[0];
    als.y = expf(es[1] - m[1]) * rden[1];
    als.z = expf(es[2] - m[2]) * rden[2];
    als.w = expf(es[3] - m[3]) * rden[3];
    *(float4*)(alpha_self + (size_t)d * 4) = als;
}

// wave-per-node weighted gather, unroll 2 edges (8 row loads in flight)
__global__ __launch_bounds__(256) void gat_gather(
    const int* __restrict__ offs, const unsigned short* __restrict__ csr,
    const float* __restrict__ alpha, const float* __restrict__ alpha_self,
    const unsigned short* __restrict__ xw, const float* __restrict__ ba,
    unsigned short* __restrict__ xcomb)
{
    int lane = threadIdx.x & 63;
    int d = (blockIdx.x * 256 + threadIdx.x) >> 6;
    if (d >= N_NODES) return;
    int base = offs[d], end = offs[d + 1];
    int c2 = lane * 2;
    float ax = 0.f, ay = 0.f;
    for (int i = base; i < end; ) {
        int chunk = min(64, end - i);
        int sv = 0;
        if (lane < chunk) sv = csr[i + lane];
        int j = 0;
        for (; j + 2 <= chunk; j += 2) {
            int sA = __shfl(sv, j), sB = __shfl(sv, j + 1);
            float4 alA = *(const float4*)(alpha + (size_t)(i + j) * 4);
            float4 alB = *(const float4*)(alpha + (size_t)(i + j + 1) * 4);
            const unsigned short* rowA = xw + (size_t)sA * 512 + c2;
            const unsigned short* rowB = xw + (size_t)sB * 512 + c2;
            unsigned a0 = *(const unsigned*)(rowA);
            unsigned a1 = *(const unsigned*)(rowA + 128);
            unsigned a2 = *(const unsigned*)(rowA + 256);
            unsigned a3 = *(const unsigned*)(rowA + 384);
            unsigned b0 = *(const unsigned*)(rowB);
            unsigned b1 = *(const unsigned*)(rowB + 128);
            unsigned b2 = *(const unsigned*)(rowB + 256);
            unsigned b3 = *(const unsigned*)(rowB + 384);
            ax = fmaf(b2f(a0), alA.x, ax); ay = fmaf(b2f(a0 >> 16), alA.x, ay);
            ax = fmaf(b2f(a1), alA.y, ax); ay = fmaf(b2f(a1 >> 16), alA.y, ay);
            ax = fmaf(b2f(a2), alA.z, ax); ay = fmaf(b2f(a2 >> 16), alA.z, ay);
            ax = fmaf(b2f(a3), alA.w, ax); ay = fmaf(b2f(a3 >> 16), alA.w, ay);
            ax = fmaf(b2f(b0), alB.x, ax); ay = fmaf(b2f(b0 >> 16), alB.x, ay);
            ax = fmaf(b2f(b1), alB.y, ax); ay = fmaf(b2f(b1 >> 16), alB.y, ay);
            ax = fmaf(b2f(b2), alB.z, ax); ay = fmaf(b2f(b2 >> 16), alB.z, ay);
            ax = fmaf(b2f(b3), alB.w, ax); ay = fmaf(b2f(b3 >> 16), alB.w, ay);
        }
        for (; j < chunk; j++) {
            int s = __shfl(sv, j);
            float4 al = *(const float4*)(alpha + (size_t)(i + j) * 4);
            const unsigned short* row = xw + (size_t)s * 512 + c2;
            unsigned u0 = *(const unsigned*)(row);
            unsigned u1 = *(const unsigned*)(row + 128);
            unsigned u2 = *(const unsigned*)(row + 256);
            unsigned u3 = *(const unsigned*)(row + 384);
            ax = fmaf(b2f(u0), al.x, ax); ay = fmaf(b2f(u0 >> 16), al.x, ay);
            ax = fmaf(b2f(u1), al.y, ax); ay = fmaf(b2f(u1 >> 16), al.y, ay);
            ax = fmaf(b2f(u2), al.z, ax); ay = fmaf(b2f(u2 >> 16), al.z, ay);
            ax = fmaf(b2f(u3), al.w, ax); ay = fmaf(b2f(u3 >> 16), al.w, ay);
        }
        i += chunk;
    }
    float4 als = *(const float4*)(alpha_self + (size_t)d * 4);
    const unsigned short* row = xw + (size_t)d * 512 + c2;
    unsigned u0 = *(const unsigned*)(row);
    unsigned u1 = *(const unsigned*)(row + 128);
    unsigned u2 = *(const unsigned*)(row + 256);
    unsigned u3 = *(const unsigned*)(row + 384);
    ax = fmaf(b2f(u0), als.x, ax); ay = fmaf(b2f(u0 >> 16), als.x, ay);
    ax = fmaf(b2f(u1), als.y, ax); ay = fmaf(b2f(u1 >> 16), als.y, ay);
    ax = fmaf(b2f(u2), als.z, ax); ay = fmaf(b2f(u2 >> 16), als.z, ay);
    ax = fmaf(b2f(u3), als.w, ax); ay = fmaf(b2f(u3 >> 16), als.w, ay);
    float ox = fmaxf(0.25f * ax + ba[c2], 0.f);
    float oy = fmaxf(0.25f * ay + ba[c2 + 1], 0.f);
    unsigned uo = (unsigned)f2b(ox) | ((unsigned)f2b(oy) << 16);
    *(unsigned*)(xcomb + (size_t)d * 256 + 128 + c2) = uo;
}

// ---------- final heads (f32 output) ----------
__global__ void final_head(const float* __restrict__ sumvec,
                           const float* __restrict__ Wc1, const float* __restrict__ bc1,
                           const float* __restrict__ Wc2, const float* __restrict__ bc2,
                           const float* __restrict__ Wu, const float* __restrict__ bu,
                           float* __restrict__ out)
{
    __shared__ float xf[128];
    __shared__ float h1[64];
    int t = threadIdx.x;   // 128 threads
    xf[t] = sumvec[t] * (1.0f / N_NODES);
    __syncthreads();
    if (t < 64) {
        float s = bc1[t];
        for (int c = 0; c < 128; c++) s = fmaf(xf[c], Wc1[c * 64 + t], s);
        h1[t] = fmaxf(s, 0.f);
    }
    __syncthreads();
    if (t < 16) {
        float s = bc2[t];
        for (int j = 0; j < 64; j++) s = fmaf(h1[j], Wc2[j * 16 + t], s);
        out[t] = s;
        float u = bu[t];
        for (int c = 0; c < 128; c++) u = fmaf(xf[c], Wu[c * 16 + t], u);
        out[16 + t] = 1.0f / (1.0f + expf(-u));
    }
}

extern "C" void kernel_launch(void* const* d_in, const int* in_sizes, int n_in,
                              void* d_out, int out_size, void* d_ws, size_t ws_size,
                              hipStream_t stream) {
    const float* x    = (const float*)d_in[0];
    const int*   lei  = (const int*)d_in[1];
    const int*   gei  = (const int*)d_in[2];
    const float* W1   = (const float*)d_in[3];
    const float* b1   = (const float*)d_in[4];
    const float* Wg   = (const float*)d_in[5];
    const float* bg   = (const float*)d_in[6];
    const float* Wa   = (const float*)d_in[7];
    const float* atts = (const float*)d_in[8];
    const float* attd = (const float*)d_in[9];
    const float* ba   = (const float*)d_in[10];
    const float* Wp   = (const float*)d_in[11];
    const float* bp   = (const float*)d_in[12];
    const float* Wc1  = (const float*)d_in[13];
    const float* bc1  = (const float*)d_in[14];
    const float* Wc2  = (const float*)d_in[15];
    const float* bc2  = (const float*)d_in[16];
    const float* Wu   = (const float*)d_in[17];
    const float* bu   = (const float*)d_in[18];

    const int* lsrc = lei;
    const int* ldst = lei + EL;
    const int* gsrc = gei;
    const int* gdst = gei + EG;

    uintptr_t base = (uintptr_t)d_ws;
    auto alloc = [&](size_t bytes) { void* p = (void*)base; base += (bytes + 255) & ~(size_t)255; return p; };
    unsigned short* xb     = (unsigned short*)alloc((size_t)N_NODES * 128 * 2);
    unsigned short* x_loc  = (unsigned short*)alloc((size_t)N_NODES * 128 * 2);
    unsigned short* xw_g   = (unsigned short*)alloc((size_t)N_NODES * 128 * 2);
    unsigned short* xw_a   = (unsigned short*)alloc((size_t)N_NODES * 512 * 2);
    unsigned short* xcomb  = (unsigned short*)alloc((size_t)N_NODES * 256 * 2);
    unsigned short* W1t    = (unsigned short*)alloc((size_t)128 * 128 * 2);
    unsigned short* Wgt    = (unsigned short*)alloc((size_t)128 * 128 * 2);
    unsigned short* Wat    = (unsigned short*)alloc((size_t)512 * 128 * 2);
    unsigned short* Wpt    = (unsigned short*)alloc((size_t)128 * 256 * 2);
    float* dinv       = (float*)alloc((size_t)N_NODES * 4);
    float* a_s        = (float*)alloc((size_t)N_NODES * 4 * 4);
    float* a_d        = (float*)alloc((size_t)N_NODES * 4 * 4);
    float* alpha_self = (float*)alloc((size_t)N_NODES * 4 * 4);
    int*   hists      = (int*)alloc((size_t)2 * N_NODES * 4);   // hist_l | hist_g contiguous
    int*   hist_l     = hists;
    int*   hist_g     = hists + N_NODES;
    int*   cur_l      = (int*)alloc((size_t)N_NODES * 4);
    int*   cur_g      = (int*)alloc((size_t)N_NODES * 4);
    int*   offs_l     = (int*)alloc(((size_t)N_NODES + 1) * 4);
    int*   offs_g     = (int*)alloc(((size_t)N_NODES + 1) * 4);
    int*   bsum_l     = (int*)alloc(256 * 4);
    int*   bsum_g     = (int*)alloc(256 * 4);
    unsigned short* csr_l = (unsigned short*)alloc((size_t)EL * 2);
    unsigned short* csr_g = (unsigned short*)alloc((size_t)EG * 2);
    float* alpha      = (float*)alloc((size_t)EG * 4 * 4);
    float* sumvec     = (float*)alloc(128 * 4);

    hipMemsetAsync(hists, 0, (size_t)2 * N_NODES * 4, stream);
    hipMemsetAsync(sumvec, 0, 128 * 4, stream);

    // conversions (x + 4 weights)
    conv_all<<<6762, 256, 0, stream>>>(x, xb, W1, W1t, Wg, Wgt, Wa, Wat, Wp, Wpt);

    // CSR build for both graphs
    hist_both<<<3907, 256, 0, stream>>>(ldst, gdst, hist_l, hist_g);
    scan_partial_both<<<2 * NB, 256, 0, stream>>>(hist_l, hist_g, bsum_l, bsum_g);
    scan_bsums_both<<<2, 256, 0, stream>>>(bsum_l, bsum_g);
    scan_final_both<<<2 * NB, 256, 0, stream>>>(hist_l, hist_g, bsum_l, bsum_g,
                                                offs_l, cur_l, offs_g, cur_g, dinv);
    fill_both<<<3907, 256, 0, stream>>>(lsrc, ldst, gsrc, gdst, cur_l, cur_g, csr_l, csr_g);

    // x_local = relu(x @ W1 + b1)
    mfma_gemm<<<dim3(GB, 1), 256, 0, stream>>>(xb, W1t, b1, x_loc, N_NODES, 128, 128, 1);

    // GCN branch
    mfma_gemm<<<dim3(GB, 1), 256, 0, stream>>>(x_loc, Wgt, nullptr, xw_g, N_NODES, 128, 128, 0);
    gcn_gather<<<12500, 256, 0, stream>>>(offs_l, csr_l, xw_g, dinv, bg, xcomb);

    // GAT branch (attn coefficients fused into GEMM epilogue)
    mfma_gemm_attn<<<dim3(GB, 4), 256, 0, stream>>>(x_loc, Wat, xw_a, N_NODES, atts, attd, a_s, a_d);
    gat_softmax<<<NB, 256, 0, stream>>>(offs_g, csr_g, a_s, a_d, alpha, alpha_self);
    gat_gather<<<12500, 256, 0, stream>>>(offs_g, csr_g, alpha, alpha_self, xw_a, ba, xcomb);

    // pool + heads
    mfma_pool<<<dim3(GB, 1), 256, 0, stream>>>(xcomb, Wpt, bp, sumvec, N_NODES);
    final_head<<<1, 128, 0, stream>>>(sumvec, Wc1, bc1, Wc2, bc2, Wu, bu,
                                      (float*)d_out);
}

// Round 7
// 232.398 us; speedup vs baseline: 5.4122x; 1.3781x over previous
//
#include <hip/hip_runtime.h>
#include <hip/hip_bf16.h>

#define N_NODES 50000
#define F_IN 128
#define HID 128
#define N_OUT 16
#define HEADS 4
#define EL 800000
#define EG 200000
#define NEG_SLOPE 0.2f
#define NB 196    // ceil(50000/256): scan blocks & buckets (256 nodes/bucket)
#define GB 391    // ceil(50000/128): GEMM row-blocks

typedef short bf16x8 __attribute__((ext_vector_type(8)));
typedef float f32x4 __attribute__((ext_vector_type(4)));

static __device__ __forceinline__ float lrelu(float x) {
    return x > 0.f ? x : NEG_SLOPE * x;
}
static __device__ __forceinline__ unsigned short f2b(float f) {
    __hip_bfloat16 h = __float2bfloat16(f);
    return *reinterpret_cast<unsigned short*>(&h);
}
static __device__ __forceinline__ float b2f(unsigned u16) {
    return __uint_as_float((u16 & 0xffffu) << 16);
}

// ---------- fused converters: x -> bf16, 4 weights -> transposed bf16 ----------
__global__ void conv_all(const float* __restrict__ x, unsigned short* __restrict__ xb,
                         const float* __restrict__ W1, unsigned short* __restrict__ W1t,
                         const float* __restrict__ Wg, unsigned short* __restrict__ Wgt,
                         const float* __restrict__ Wa, unsigned short* __restrict__ Wat,
                         const float* __restrict__ Wp, unsigned short* __restrict__ Wpt)
{
    int b = blockIdx.x, t = threadIdx.x;
    if (b < 6250) {                       // x: N*128/4 = 1.6M vec4
        int i = b * 256 + t;
        float4 v = *(const float4*)(x + 4 * (size_t)i);
        ushort4 o;
        o.x = f2b(v.x); o.y = f2b(v.y); o.z = f2b(v.z); o.w = f2b(v.w);
        *(ushort4*)(xb + 4 * (size_t)i) = o;
    } else if (b < 6314) {                // W1 [128][128]
        int idx = (b - 6250) * 256 + t;
        int k = idx >> 7, n = idx & 127;
        W1t[n * 128 + k] = f2b(W1[idx]);
    } else if (b < 6378) {                // Wg [128][128]
        int idx = (b - 6314) * 256 + t;
        int k = idx >> 7, n = idx & 127;
        Wgt[n * 128 + k] = f2b(Wg[idx]);
    } else if (b < 6634) {                // Wa [128][512]
        int idx = (b - 6378) * 256 + t;
        int k = idx >> 9, n = idx & 511;
        Wat[(size_t)n * 128 + k] = f2b(Wa[idx]);
    } else {                              // Wp [256][128]
        int idx = (b - 6634) * 256 + t;
        int k = idx >> 7, n = idx & 127;
        Wpt[(size_t)n * 256 + k] = f2b(Wp[idx]);
    }
}

// ---------- bucket CSR build ----------
// A1: per-block LDS bucket histogram -> 196 global atomics/block
__global__ __launch_bounds__(256) void bucket_hist(
    const int* __restrict__ ldst, const int* __restrict__ gdst, int* __restrict__ ghist)
{
    __shared__ int lh[NB];
    int blk = blockIdx.x, t = threadIdx.x;
    bool loc = blk < 196;
    const int* dstp = loc ? ldst : gdst;
    int nE = loc ? EL : EG;
    int* gh = ghist + (loc ? 0 : NB);
    int start = (loc ? blk : blk - 196) * 4096;
    if (t < NB) lh[t] = 0;
    __syncthreads();
    #pragma unroll
    for (int i = 0; i < 16; i++) {
        int e = start + i * 256 + t;
        if (e < nE) atomicAdd(&lh[dstp[e] >> 8], 1);
    }
    __syncthreads();
    if (t < NB && lh[t]) atomicAdd(&gh[t], lh[t]);
}
// A2: exclusive scan of bucket counts (one block per graph); init cursors
__global__ void bucket_scan(const int* __restrict__ ghist,
                            int* __restrict__ bbase, int* __restrict__ gcur)
{
    __shared__ int s[256];
    int g = blockIdx.x, t = threadIdx.x;
    int v = (t < NB) ? ghist[g * NB + t] : 0;
    s[t] = v;
    __syncthreads();
    for (int off = 1; off < 256; off <<= 1) {
        int u = (t >= off) ? s[t - off] : 0;
        __syncthreads();
        s[t] += u;
        __syncthreads();
    }
    if (t < NB) {
        bbase[g * (NB + 1) + t] = s[t] - v;
        gcur[g * NB + t] = s[t] - v;
    }
    if (t == NB - 1) bbase[g * (NB + 1) + NB] = s[t];
}
// A3: partition edges into bucket-contiguous ebuf; 1 global atomic/(block,bucket)
__global__ __launch_bounds__(256) void bucket_part(
    const int* __restrict__ lsrc, const int* __restrict__ ldst,
    const int* __restrict__ gsrc, const int* __restrict__ gdst,
    int* __restrict__ gcur, unsigned* __restrict__ ebuf_l, unsigned* __restrict__ ebuf_g)
{
    __shared__ int lhist[NB], lbase[NB];
    int blk = blockIdx.x, t = threadIdx.x;
    bool loc = blk < 196;
    const int* srcp = loc ? lsrc : gsrc;
    const int* dstp = loc ? ldst : gdst;
    int nE = loc ? EL : EG;
    unsigned* ebuf = loc ? ebuf_l : ebuf_g;
    int* cur = gcur + (loc ? 0 : NB);
    int start = (loc ? blk : blk - 196) * 4096;
    if (t < NB) lhist[t] = 0;
    __syncthreads();
    unsigned pk[16];
    #pragma unroll
    for (int i = 0; i < 16; i++) {
        int e = start + i * 256 + t;
        if (e < nE) {
            unsigned d = (unsigned)dstp[e];
            pk[i] = (d << 16) | (unsigned)srcp[e];
            atomicAdd(&lhist[d >> 8], 1);
        } else pk[i] = 0xFFFFFFFFu;
    }
    __syncthreads();
    if (t < NB) lbase[t] = atomicAdd(&cur[t], lhist[t]);
    __syncthreads();
    if (t < NB) lhist[t] = 0;
    __syncthreads();
    #pragma unroll
    for (int i = 0; i < 16; i++) {
        unsigned b = pk[i] >> 24;
        if (b < NB) {
            int r = atomicAdd(&lhist[b], 1);
            ebuf[lbase[b] + r] = pk[i];
        }
    }
}
// B: per-bucket fine CSR (count -> LDS scan -> offs/dinv -> place)
__global__ __launch_bounds__(256) void bucket_csr(
    const unsigned* __restrict__ ebuf_l, const unsigned* __restrict__ ebuf_g,
    const int* __restrict__ bbase,
    int* __restrict__ offs_l, int* __restrict__ offs_g,
    unsigned short* __restrict__ csr_l, unsigned short* __restrict__ csr_g,
    float* __restrict__ dinv)
{
    __shared__ int cnt[256], s[256], cur[256];
    int blk = blockIdx.x, t = threadIdx.x;
    bool loc = blk < 196;
    int b = loc ? blk : blk - 196;
    const unsigned* ebuf = loc ? ebuf_l : ebuf_g;
    const int* bb = bbase + (loc ? 0 : NB + 1);
    int* offs = loc ? offs_l : offs_g;
    unsigned short* csr = loc ? csr_l : csr_g;
    int rs = bb[b], re = bb[b + 1];
    cnt[t] = 0;
    __syncthreads();
    for (int i = rs + t; i < re; i += 256) atomicAdd(&cnt[(ebuf[i] >> 16) & 255], 1);
    __syncthreads();
    int v = cnt[t];
    s[t] = v;
    __syncthreads();
    for (int off = 1; off < 256; off <<= 1) {
        int u = (t >= off) ? s[t - off] : 0;
        __syncthreads();
        s[t] += u;
        __syncthreads();
    }
    int excl = s[t] - v;
    int node = b * 256 + t;
    cur[t] = rs + excl;
    if (node < N_NODES) {
        offs[node] = rs + excl;
        if (loc) dinv[node] = rsqrtf((float)(v + 1));
    }
    if (blk == 0 && t == 0) offs_l[N_NODES] = EL;
    if (blk == 196 && t == 0) offs_g[N_NODES] = EG;
    __syncthreads();
    for (int i = rs + t; i < re; i += 256) {
        unsigned pk = ebuf[i];
        int r = atomicAdd(&cur[(pk >> 16) & 255], 1);
        csr[r] = (unsigned short)(pk & 0xFFFFu);
    }
}

// ---------- MFMA GEMM: out[M,N] = act(A[M,K] @ Bt[N,K]^T + bias), bf16 in/out ----------
__global__ __launch_bounds__(256) void mfma_gemm(
    const unsigned short* __restrict__ A, const unsigned short* __restrict__ Bt,
    const float* __restrict__ bias, unsigned short* __restrict__ out,
    int M, int K, int N, int relu_act)
{
    __shared__ unsigned short As[128 * 128];
    __shared__ unsigned short Bs[128 * 128];
    int tid = threadIdx.x;
    int lane = tid & 63, w = tid >> 6;
    int wr = w >> 1, wc = w & 1;
    int l16 = lane & 15, lhi = lane >> 4;
    int m0 = blockIdx.x * 128, n0 = blockIdx.y * 128;
    f32x4 acc[4][4] = {};
    for (int kb = 0; kb < K; kb += 128) {
        if (kb) __syncthreads();
        #pragma unroll
        for (int i = 0; i < 8; i++) {
            int u = tid + i * 256;
            int row = u >> 4, e0 = (u & 15) << 3;
            int sw = e0 ^ ((row & 7) << 3);
            bf16x8 va = {};
            int gr = m0 + row;
            if (gr < M) va = *(const bf16x8*)(A + (size_t)gr * K + kb + e0);
            *(bf16x8*)(As + row * 128 + sw) = va;
            int gn = n0 + row;
            bf16x8 vb = *(const bf16x8*)(Bt + (size_t)gn * K + kb + e0);
            *(bf16x8*)(Bs + row * 128 + sw) = vb;
        }
        __syncthreads();
        #pragma unroll
        for (int kk = 0; kk < 4; kk++) {
            int ke = kk * 32 + lhi * 8;
            bf16x8 af[4], bfr[4];
            #pragma unroll
            for (int m = 0; m < 4; m++) {
                int r = wr * 64 + m * 16 + l16;
                af[m] = *(const bf16x8*)(As + r * 128 + (ke ^ ((r & 7) << 3)));
            }
            #pragma unroll
            for (int n = 0; n < 4; n++) {
                int r = wc * 64 + n * 16 + l16;
                bfr[n] = *(const bf16x8*)(Bs + r * 128 + (ke ^ ((r & 7) << 3)));
            }
            #pragma unroll
            for (int m = 0; m < 4; m++)
                #pragma unroll
                for (int n = 0; n < 4; n++)
                    acc[m][n] = __builtin_amdgcn_mfma_f32_16x16x32_bf16(af[m], bfr[n], acc[m][n], 0, 0, 0);
        }
    }
    #pragma unroll
    for (int m = 0; m < 4; m++) {
        #pragma unroll
        for (int r = 0; r < 4; r++) {
            int row_g = m0 + wr * 64 + m * 16 + lhi * 4 + r;
            if (row_g >= M) continue;
            #pragma unroll
            for (int n = 0; n < 4; n++) {
                int col_g = n0 + wc * 64 + n * 16 + l16;
                float v = acc[m][n][r];
                if (bias) v += bias[col_g];
                if (relu_act) v = fmaxf(v, 0.f);
                out[(size_t)row_g * N + col_g] = f2b(v);
            }
        }
    }
}

// ---------- MFMA GEMM for Wa with fused attention-coefficient epilogue ----------
__global__ __launch_bounds__(256) void mfma_gemm_attn(
    const unsigned short* __restrict__ A, const unsigned short* __restrict__ Bt,
    unsigned short* __restrict__ out, int M,
    const float* __restrict__ atts, const float* __restrict__ attd,
    float* __restrict__ a_s, float* __restrict__ a_d)
{
    __shared__ unsigned short As[128 * 128];
    __shared__ unsigned short Bs[128 * 128];
    __shared__ float sas[128], sad[128];
    int tid = threadIdx.x;
    int lane = tid & 63, w = tid >> 6;
    int wr = w >> 1, wc = w & 1;
    int l16 = lane & 15, lhi = lane >> 4;
    int m0 = blockIdx.x * 128, n0 = blockIdx.y * 128;
    int head = blockIdx.y;
    f32x4 acc[4][4] = {};
    {
        #pragma unroll
        for (int i = 0; i < 8; i++) {
            int u = tid + i * 256;
            int row = u >> 4, e0 = (u & 15) << 3;
            int sw = e0 ^ ((row & 7) << 3);
            bf16x8 va = {};
            int gr = m0 + row;
            if (gr < M) va = *(const bf16x8*)(A + (size_t)gr * 128 + e0);
            *(bf16x8*)(As + row * 128 + sw) = va;
            int gn = n0 + row;
            bf16x8 vb = *(const bf16x8*)(Bt + (size_t)gn * 128 + e0);
            *(bf16x8*)(Bs + row * 128 + sw) = vb;
        }
        if (tid < 128) { sas[tid] = 0.f; sad[tid] = 0.f; }
        __syncthreads();
        #pragma unroll
        for (int kk = 0; kk < 4; kk++) {
            int ke = kk * 32 + lhi * 8;
            bf16x8 af[4], bfr[4];
            #pragma unroll
            for (int m = 0; m < 4; m++) {
                int r = wr * 64 + m * 16 + l16;
                af[m] = *(const bf16x8*)(As + r * 128 + (ke ^ ((r & 7) << 3)));
            }
            #pragma unroll
            for (int n = 0; n < 4; n++) {
                int r = wc * 64 + n * 16 + l16;
                bfr[n] = *(const bf16x8*)(Bs + r * 128 + (ke ^ ((r & 7) << 3)));
            }
            #pragma unroll
            for (int m = 0; m < 4; m++)
                #pragma unroll
                for (int n = 0; n < 4; n++)
                    acc[m][n] = __builtin_amdgcn_mfma_f32_16x16x32_bf16(af[m], bfr[n], acc[m][n], 0, 0, 0);
        }
    }
    float ats[4], atd[4];
    #pragma unroll
    for (int n = 0; n < 4; n++) {
        int cl = wc * 64 + n * 16 + l16;
        ats[n] = atts[head * 128 + cl];
        atd[n] = attd[head * 128 + cl];
    }
    #pragma unroll
    for (int m = 0; m < 4; m++) {
        #pragma unroll
        for (int r = 0; r < 4; r++) {
            int row_l = wr * 64 + m * 16 + lhi * 4 + r;
            int row_g = m0 + row_l;
            float ps = 0.f, pd = 0.f;
            #pragma unroll
            for (int n = 0; n < 4; n++) {
                float v = acc[m][n][r];
                ps = fmaf(v, ats[n], ps);
                pd = fmaf(v, atd[n], pd);
                if (row_g < M) {
                    int col_g = n0 + wc * 64 + n * 16 + l16;
                    out[(size_t)row_g * 512 + col_g] = f2b(v);
                }
            }
            #pragma unroll
            for (int off = 1; off < 16; off <<= 1) {
                ps += __shfl_xor(ps, off);
                pd += __shfl_xor(pd, off);
            }
            if (l16 == 0) {
                atomicAdd(&sas[row_l], ps);
                atomicAdd(&sad[row_l], pd);
            }
        }
    }
    __syncthreads();
    if (tid < 128) {
        int row_g = m0 + tid;
        if (row_g < M) {
            a_s[(size_t)row_g * 4 + head] = sas[tid];
            a_d[(size_t)row_g * 4 + head] = sad[tid];
        }
    }
}

// ---------- MFMA pooled GEMM + column-mean accumulation (K=256, N=128) ----------
__global__ __launch_bounds__(256) void mfma_pool(
    const unsigned short* __restrict__ A, const unsigned short* __restrict__ Bt,
    const float* __restrict__ bp, float* __restrict__ sumvec, int M)
{
    __shared__ unsigned short As[128 * 128];
    __shared__ unsigned short Bs[128 * 128];
    __shared__ float red[128];
    int tid = threadIdx.x;
    int lane = tid & 63, w = tid >> 6;
    int wr = w >> 1, wc = w & 1;
    int l16 = lane & 15, lhi = lane >> 4;
    int m0 = blockIdx.x * 128;
    f32x4 acc[4][4] = {};
    for (int kb = 0; kb < 256; kb += 128) {
        if (kb) __syncthreads();
        #pragma unroll
        for (int i = 0; i < 8; i++) {
            int u = tid + i * 256;
            int row = u >> 4, e0 = (u & 15) << 3;
            int sw = e0 ^ ((row & 7) << 3);
            bf16x8 va = {};
            int gr = m0 + row;
            if (gr < M) va = *(const bf16x8*)(A + (size_t)gr * 256 + kb + e0);
            *(bf16x8*)(As + row * 128 + sw) = va;
            bf16x8 vb = *(const bf16x8*)(Bt + (size_t)row * 256 + kb + e0);
            *(bf16x8*)(Bs + row * 128 + sw) = vb;
        }
        __syncthreads();
        #pragma unroll
        for (int kk = 0; kk < 4; kk++) {
            int ke = kk * 32 + lhi * 8;
            bf16x8 af[4], bfr[4];
            #pragma unroll
            for (int m = 0; m < 4; m++) {
                int r = wr * 64 + m * 16 + l16;
                af[m] = *(const bf16x8*)(As + r * 128 + (ke ^ ((r & 7) << 3)));
            }
            #pragma unroll
            for (int n = 0; n < 4; n++) {
                int r = wc * 64 + n * 16 + l16;
                bfr[n] = *(const bf16x8*)(Bs + r * 128 + (ke ^ ((r & 7) << 3)));
            }
            #pragma unroll
            for (int m = 0; m < 4; m++)
                #pragma unroll
                for (int n = 0; n < 4; n++)
                    acc[m][n] = __builtin_amdgcn_mfma_f32_16x16x32_bf16(af[m], bfr[n], acc[m][n], 0, 0, 0);
        }
    }
    float bcol[4];
    #pragma unroll
    for (int n = 0; n < 4; n++) bcol[n] = bp[wc * 64 + n * 16 + l16];
    float colsum[4] = {0.f, 0.f, 0.f, 0.f};
    #pragma unroll
    for (int m = 0; m < 4; m++) {
        #pragma unroll
        for (int r = 0; r < 4; r++) {
            int row_g = m0 + wr * 64 + m * 16 + lhi * 4 + r;
            if (row_g < M) {
                #pragma unroll
                for (int n = 0; n < 4; n++)
                    colsum[n] += fmaxf(acc[m][n][r] + bcol[n], 0.f);
            }
        }
    }
    #pragma unroll
    for (int n = 0; n < 4; n++) {
        colsum[n] += __shfl_xor(colsum[n], 16);
        colsum[n] += __shfl_xor(colsum[n], 32);
    }
    if (tid < 128) red[tid] = 0.f;
    __syncthreads();
    if (lhi == 0) {
        #pragma unroll
        for (int n = 0; n < 4; n++)
            atomicAdd(&red[wc * 64 + n * 16 + l16], colsum[n]);
    }
    __syncthreads();
    if (tid < 128) atomicAdd(&sumvec[tid], red[tid]);
}

// ---------- GAT per-node softmax ----------
__global__ void gat_softmax(const int* __restrict__ offs, const unsigned short* __restrict__ csr,
                            const float* __restrict__ a_s, const float* __restrict__ a_d,
                            float* __restrict__ alpha, float* __restrict__ alpha_self)
{
    int d = blockIdx.x * 256 + threadIdx.x;
    if (d >= N_NODES) return;
    int base = offs[d], end = offs[d + 1];
    float4 ad = *(const float4*)(a_d + (size_t)d * 4);
    float4 asd = *(const float4*)(a_s + (size_t)d * 4);
    float es[4] = {lrelu(asd.x + ad.x), lrelu(asd.y + ad.y),
                   lrelu(asd.z + ad.z), lrelu(asd.w + ad.w)};
    float m[4] = {es[0], es[1], es[2], es[3]};
    for (int p = base; p < end; p++) {
        int s = csr[p];
        float4 as4 = *(const float4*)(a_s + (size_t)s * 4);
        m[0] = fmaxf(m[0], lrelu(as4.x + ad.x));
        m[1] = fmaxf(m[1], lrelu(as4.y + ad.y));
        m[2] = fmaxf(m[2], lrelu(as4.z + ad.z));
        m[3] = fmaxf(m[3], lrelu(as4.w + ad.w));
    }
    float den[4];
    #pragma unroll
    for (int h = 0; h < 4; h++) den[h] = expf(es[h] - m[h]);
    for (int p = base; p < end; p++) {
        int s = csr[p];
        float4 as4 = *(const float4*)(a_s + (size_t)s * 4);
        den[0] += expf(lrelu(as4.x + ad.x) - m[0]);
        den[1] += expf(lrelu(as4.y + ad.y) - m[1]);
        den[2] += expf(lrelu(as4.z + ad.z) - m[2]);
        den[3] += expf(lrelu(as4.w + ad.w) - m[3]);
    }
    float rden[4];
    #pragma unroll
    for (int h = 0; h < 4; h++) rden[h] = 1.0f / (den[h] + 1e-16f);
    for (int p = base; p < end; p++) {
        int s = csr[p];
        float4 as4 = *(const float4*)(a_s + (size_t)s * 4);
        float4 al;
        al.x = expf(lrelu(as4.x + ad.x) - m[0]) * rden[0];
        al.y = expf(lrelu(as4.y + ad.y) - m[1]) * rden[1];
        al.z = expf(lrelu(as4.z + ad.z) - m[2]) * rden[2];
        al.w = expf(lrelu(as4.w + ad.w) - m[3]) * rden[3];
        *(float4*)(alpha + (size_t)p * 4) = al;
    }
    float4 als;
    als.x = expf(es[0] - m[0]) * rden[0];
    als.y = expf(es[1] - m[1]) * rden[1];
    als.z = expf(es[2] - m[2]) * rden[2];
    als.w = expf(es[3] - m[3]) * rden[3];
    *(float4*)(alpha_self + (size_t)d * 4) = als;
}

// ---------- fused gathers: blocks [0,12500) = GCN, [12500,25000) = GAT ----------
__global__ __launch_bounds__(256) void fused_gather(
    const int* __restrict__ offs_l, const unsigned short* __restrict__ csr_l,
    const unsigned short* __restrict__ xw_g, const float* __restrict__ dinv,
    const float* __restrict__ bg,
    const int* __restrict__ offs_g, const unsigned short* __restrict__ csr_g,
    const float* __restrict__ alpha, const float* __restrict__ alpha_self,
    const unsigned short* __restrict__ xw_a, const float* __restrict__ ba,
    unsigned short* __restrict__ xcomb)
{
    int blk = blockIdx.x;
    int lane = threadIdx.x & 63;
    int c2 = lane * 2;
    if (blk < 12500) {
        int d = (blk * 256 + threadIdx.x) >> 6;
        if (d >= N_NODES) return;
        int base = offs_l[d], end = offs_l[d + 1];
        float ax = 0.f, ay = 0.f;
        for (int i = base; i < end; ) {
            int chunk = min(64, end - i);
            int sv = 0; float dvv = 0.f;
            if (lane < chunk) { sv = csr_l[i + lane]; dvv = dinv[sv]; }
            int j = 0;
            for (; j + 4 <= chunk; j += 4) {
                int s0 = __shfl(sv, j),     s1 = __shfl(sv, j + 1);
                int s2 = __shfl(sv, j + 2), s3 = __shfl(sv, j + 3);
                float d0 = __shfl(dvv, j),     d1 = __shfl(dvv, j + 1);
                float d2 = __shfl(dvv, j + 2), d3 = __shfl(dvv, j + 3);
                unsigned u0 = *(const unsigned*)(xw_g + (size_t)s0 * 128 + c2);
                unsigned u1 = *(const unsigned*)(xw_g + (size_t)s1 * 128 + c2);
                unsigned u2 = *(const unsigned*)(xw_g + (size_t)s2 * 128 + c2);
                unsigned u3 = *(const unsigned*)(xw_g + (size_t)s3 * 128 + c2);
                ax = fmaf(b2f(u0), d0, ax); ay = fmaf(b2f(u0 >> 16), d0, ay);
                ax = fmaf(b2f(u1), d1, ax); ay = fmaf(b2f(u1 >> 16), d1, ay);
                ax = fmaf(b2f(u2), d2, ax); ay = fmaf(b2f(u2 >> 16), d2, ay);
                ax = fmaf(b2f(u3), d3, ax); ay = fmaf(b2f(u3 >> 16), d3, ay);
            }
            for (; j < chunk; j++) {
                int s = __shfl(sv, j);
                float dv = __shfl(dvv, j);
                unsigned u = *(const unsigned*)(xw_g + (size_t)s * 128 + c2);
                ax = fmaf(b2f(u), dv, ax);
                ay = fmaf(b2f(u >> 16), dv, ay);
            }
            i += chunk;
        }
        float dd = dinv[d];
        unsigned us = *(const unsigned*)(xw_g + (size_t)d * 128 + c2);
        float ox = fmaxf(dd * ax + dd * dd * b2f(us) + bg[c2], 0.f);
        float oy = fmaxf(dd * ay + dd * dd * b2f(us >> 16) + bg[c2 + 1], 0.f);
        unsigned uo = (unsigned)f2b(ox) | ((unsigned)f2b(oy) << 16);
        *(unsigned*)(xcomb + (size_t)d * 256 + c2) = uo;
    } else {
        int d = ((blk - 12500) * 256 + threadIdx.x) >> 6;
        if (d >= N_NODES) return;
        int base = offs_g[d], end = offs_g[d + 1];
        float ax = 0.f, ay = 0.f;
        for (int i = base; i < end; ) {
            int chunk = min(64, end - i);
            int sv = 0;
            if (lane < chunk) sv = csr_g[i + lane];
            int j = 0;
            for (; j + 2 <= chunk; j += 2) {
                int sA = __shfl(sv, j), sB = __shfl(sv, j + 1);
                float4 alA = *(const float4*)(alpha + (size_t)(i + j) * 4);
                float4 alB = *(const float4*)(alpha + (size_t)(i + j + 1) * 4);
                const unsigned short* rowA = xw_a + (size_t)sA * 512 + c2;
                const unsigned short* rowB = xw_a + (size_t)sB * 512 + c2;
                unsigned a0 = *(const unsigned*)(rowA);
                unsigned a1 = *(const unsigned*)(rowA + 128);
                unsigned a2 = *(const unsigned*)(rowA + 256);
                unsigned a3 = *(const unsigned*)(rowA + 384);
                unsigned b0 = *(const unsigned*)(rowB);
                unsigned b1 = *(const unsigned*)(rowB + 128);
                unsigned b2 = *(const unsigned*)(rowB + 256);
                unsigned b3 = *(const unsigned*)(rowB + 384);
                ax = fmaf(b2f(a0), alA.x, ax); ay = fmaf(b2f(a0 >> 16), alA.x, ay);
                ax = fmaf(b2f(a1), alA.y, ax); ay = fmaf(b2f(a1 >> 16), alA.y, ay);
                ax = fmaf(b2f(a2), alA.z, ax); ay = fmaf(b2f(a2 >> 16), alA.z, ay);
                ax = fmaf(b2f(a3), alA.w, ax); ay = fmaf(b2f(a3 >> 16), alA.w, ay);
                ax = fmaf(b2f(b0), alB.x, ax); ay = fmaf(b2f(b0 >> 16), alB.x, ay);
                ax = fmaf(b2f(b1), alB.y, ax); ay = fmaf(b2f(b1 >> 16), alB.y, ay);
                ax = fmaf(b2f(b2), alB.z, ax); ay = fmaf(b2f(b2 >> 16), alB.z, ay);
                ax = fmaf(b2f(b3), alB.w, ax); ay = fmaf(b2f(b3 >> 16), alB.w, ay);
            }
            for (; j < chunk; j++) {
                int s = __shfl(sv, j);
                float4 al = *(const float4*)(alpha + (size_t)(i + j) * 4);
                const unsigned short* row = xw_a + (size_t)s * 512 + c2;
                unsigned u0 = *(const unsigned*)(row);
                unsigned u1 = *(const unsigned*)(row + 128);
                unsigned u2 = *(const unsigned*)(row + 256);
                unsigned u3 = *(const unsigned*)(row + 384);
                ax = fmaf(b2f(u0), al.x, ax); ay = fmaf(b2f(u0 >> 16), al.x, ay);
                ax = fmaf(b2f(u1), al.y, ax); ay = fmaf(b2f(u1 >> 16), al.y, ay);
                ax = fmaf(b2f(u2), al.z, ax); ay = fmaf(b2f(u2 >> 16), al.z, ay);
                ax = fmaf(b2f(u3), al.w, ax); ay = fmaf(b2f(u3 >> 16), al.w, ay);
            }
            i += chunk;
        }
        float4 als = *(const float4*)(alpha_self + (size_t)d * 4);
        const unsigned short* row = xw_a + (size_t)d * 512 + c2;
        unsigned u0 = *(const unsigned*)(row);
        unsigned u1 = *(const unsigned*)(row + 128);
        unsigned u2 = *(const unsigned*)(row + 256);
        unsigned u3 = *(const unsigned*)(row + 384);
        ax = fmaf(b2f(u0), als.x, ax); ay = fmaf(b2f(u0 >> 16), als.x, ay);
        ax = fmaf(b2f(u1), als.y, ax); ay = fmaf(b2f(u1 >> 16), als.y, ay);
        ax = fmaf(b2f(u2), als.z, ax); ay = fmaf(b2f(u2 >> 16), als.z, ay);
        ax = fmaf(b2f(u3), als.w, ax); ay = fmaf(b2f(u3 >> 16), als.w, ay);
        float ox = fmaxf(0.25f * ax + ba[c2], 0.f);
        float oy = fmaxf(0.25f * ay + ba[c2 + 1], 0.f);
        unsigned uo = (unsigned)f2b(ox) | ((unsigned)f2b(oy) << 16);
        *(unsigned*)(xcomb + (size_t)d * 256 + 128 + c2) = uo;
    }
}

// ---------- final heads (f32 output) ----------
__global__ void final_head(const float* __restrict__ sumvec,
                           const float* __restrict__ Wc1, const float* __restrict__ bc1,
                           const float* __restrict__ Wc2, const float* __restrict__ bc2,
                           const float* __restrict__ Wu, const float* __restrict__ bu,
                           float* __restrict__ out)
{
    __shared__ float xf[128];
    __shared__ float h1[64];
    int t = threadIdx.x;   // 128 threads
    xf[t] = sumvec[t] * (1.0f / N_NODES);
    __syncthreads();
    if (t < 64) {
        float s = bc1[t];
        for (int c = 0; c < 128; c++) s = fmaf(xf[c], Wc1[c * 64 + t], s);
        h1[t] = fmaxf(s, 0.f);
    }
    __syncthreads();
    if (t < 16) {
        float s = bc2[t];
        for (int j = 0; j < 64; j++) s = fmaf(h1[j], Wc2[j * 16 + t], s);
        out[t] = s;
        float u = bu[t];
        for (int c = 0; c < 128; c++) u = fmaf(xf[c], Wu[c * 16 + t], u);
        out[16 + t] = 1.0f / (1.0f + expf(-u));
    }
}

extern "C" void kernel_launch(void* const* d_in, const int* in_sizes, int n_in,
                              void* d_out, int out_size, void* d_ws, size_t ws_size,
                              hipStream_t stream) {
    const float* x    = (const float*)d_in[0];
    const int*   lei  = (const int*)d_in[1];
    const int*   gei  = (const int*)d_in[2];
    const float* W1   = (const float*)d_in[3];
    const float* b1   = (const float*)d_in[4];
    const float* Wg   = (const float*)d_in[5];
    const float* bg   = (const float*)d_in[6];
    const float* Wa   = (const float*)d_in[7];
    const float* atts = (const float*)d_in[8];
    const float* attd = (const float*)d_in[9];
    const float* ba   = (const float*)d_in[10];
    const float* Wp   = (const float*)d_in[11];
    const float* bp   = (const float*)d_in[12];
    const float* Wc1  = (const float*)d_in[13];
    const float* bc1  = (const float*)d_in[14];
    const float* Wc2  = (const float*)d_in[15];
    const float* bc2  = (const float*)d_in[16];
    const float* Wu   = (const float*)d_in[17];
    const float* bu   = (const float*)d_in[18];

    const int* lsrc = lei;
    const int* ldst = lei + EL;
    const int* gsrc = gei;
    const int* gdst = gei + EG;

    uintptr_t base = (uintptr_t)d_ws;
    auto alloc = [&](size_t bytes) { void* p = (void*)base; base += (bytes + 255) & ~(size_t)255; return p; };
    unsigned short* xb     = (unsigned short*)alloc((size_t)N_NODES * 128 * 2);
    unsigned short* x_loc  = (unsigned short*)alloc((size_t)N_NODES * 128 * 2);
    unsigned short* xw_g   = (unsigned short*)alloc((size_t)N_NODES * 128 * 2);
    unsigned short* xw_a   = (unsigned short*)alloc((size_t)N_NODES * 512 * 2);
    unsigned short* xcomb  = (unsigned short*)alloc((size_t)N_NODES * 256 * 2);
    unsigned short* W1t    = (unsigned short*)alloc((size_t)128 * 128 * 2);
    unsigned short* Wgt    = (unsigned short*)alloc((size_t)128 * 128 * 2);
    unsigned short* Wat    = (unsigned short*)alloc((size_t)512 * 128 * 2);
    unsigned short* Wpt    = (unsigned short*)alloc((size_t)128 * 256 * 2);
    float* dinv       = (float*)alloc((size_t)N_NODES * 4);
    float* a_s        = (float*)alloc((size_t)N_NODES * 4 * 4);
    float* a_d        = (float*)alloc((size_t)N_NODES * 4 * 4);
    float* alpha_self = (float*)alloc((size_t)N_NODES * 4 * 4);
    int*   ghist      = (int*)alloc((size_t)2 * NB * 4);
    int*   bbase      = (int*)alloc((size_t)2 * (NB + 1) * 4);
    int*   gcur       = (int*)alloc((size_t)2 * NB * 4);
    unsigned* ebuf_l  = (unsigned*)alloc((size_t)EL * 4);
    unsigned* ebuf_g  = (unsigned*)alloc((size_t)EG * 4);
    int*   offs_l     = (int*)alloc(((size_t)N_NODES + 1) * 4);
    int*   offs_g     = (int*)alloc(((size_t)N_NODES + 1) * 4);
    unsigned short* csr_l = (unsigned short*)alloc((size_t)EL * 2);
    unsigned short* csr_g = (unsigned short*)alloc((size_t)EG * 2);
    float* alpha      = (float*)alloc((size_t)EG * 4 * 4);
    float* sumvec     = (float*)alloc(128 * 4);

    hipMemsetAsync(ghist, 0, (size_t)2 * NB * 4, stream);
    hipMemsetAsync(sumvec, 0, 128 * 4, stream);

    // conversions (x + 4 weights)
    conv_all<<<6762, 256, 0, stream>>>(x, xb, W1, W1t, Wg, Wgt, Wa, Wat, Wp, Wpt);

    // bucket CSR build: 196 local tiles + 49 global tiles
    bucket_hist<<<245, 256, 0, stream>>>(ldst, gdst, ghist);
    bucket_scan<<<2, 256, 0, stream>>>(ghist, bbase, gcur);
    bucket_part<<<245, 256, 0, stream>>>(lsrc, ldst, gsrc, gdst, gcur, ebuf_l, ebuf_g);
    bucket_csr<<<392, 256, 0, stream>>>(ebuf_l, ebuf_g, bbase, offs_l, offs_g,
                                        csr_l, csr_g, dinv);

    // x_local = relu(x @ W1 + b1)
    mfma_gemm<<<dim3(GB, 1), 256, 0, stream>>>(xb, W1t, b1, x_loc, N_NODES, 128, 128, 1);

    // feature GEMMs
    mfma_gemm<<<dim3(GB, 1), 256, 0, stream>>>(x_loc, Wgt, nullptr, xw_g, N_NODES, 128, 128, 0);
    mfma_gemm_attn<<<dim3(GB, 4), 256, 0, stream>>>(x_loc, Wat, xw_a, N_NODES, atts, attd, a_s, a_d);

    // GAT softmax, then both gathers fused (co-resident for latency overlap)
    gat_softmax<<<NB, 256, 0, stream>>>(offs_g, csr_g, a_s, a_d, alpha, alpha_self);
    fused_gather<<<25000, 256, 0, stream>>>(offs_l, csr_l, xw_g, dinv, bg,
                                            offs_g, csr_g, alpha, alpha_self, xw_a, ba, xcomb);

    // pool + heads
    mfma_pool<<<dim3(GB, 1), 256, 0, stream>>>(xcomb, Wpt, bp, sumvec, N_NODES);
    final_head<<<1, 128, 0, stream>>>(sumvec, Wc1, bc1, Wc2, bc2, Wu, bu,
                                      (float*)d_out);
}

// Round 8
// 193.558 us; speedup vs baseline: 6.4982x; 1.2007x over previous
//
#include <hip/hip_runtime.h>
#include <hip/hip_bf16.h>

#define N_NODES 50000
#define F_IN 128
#define HID 128
#define N_OUT 16
#define HEADS 4
#define EL 800000
#define EG 200000
#define NEG_SLOPE 0.2f
#define NB 196    // buckets of 256 nodes
#define GB 391    // ceil(50000/128)

typedef short bf16x8 __attribute__((ext_vector_type(8)));
typedef float f32x4 __attribute__((ext_vector_type(4)));
typedef float f32x2 __attribute__((ext_vector_type(2)));

static __device__ __forceinline__ float lrelu(float x) {
    return x > 0.f ? x : NEG_SLOPE * x;
}
static __device__ __forceinline__ unsigned short f2b(float f) {
    __hip_bfloat16 h = __float2bfloat16(f);
    return *reinterpret_cast<unsigned short*>(&h);
}
static __device__ __forceinline__ unsigned char f2fp8(float f) {
    unsigned pk = __builtin_amdgcn_cvt_pk_fp8_f32(f, f, 0, false);
    return (unsigned char)(pk & 0xFF);
}
static __device__ __forceinline__ f32x2 fp8x2_to_f32(unsigned u) {
    return __builtin_amdgcn_cvt_pk_f32_fp8((int)u, false);
}

// ---------- fused: weight conversions + bucket histogram ----------
__global__ __launch_bounds__(256) void conv_hist(
    const float* __restrict__ W1, unsigned short* __restrict__ W1t,
    const float* __restrict__ Wg, unsigned short* __restrict__ Wgt,
    const float* __restrict__ Wa, unsigned short* __restrict__ Wat,
    const float* __restrict__ Wp, unsigned short* __restrict__ Wpt,
    const int* __restrict__ ldst, const int* __restrict__ gdst, int* __restrict__ ghist)
{
    int b = blockIdx.x, t = threadIdx.x;
    if (b < 64) {                         // W1 [128][128] -> [n][k]
        int idx = b * 256 + t;
        int k = idx >> 7, n = idx & 127;
        W1t[n * 128 + k] = f2b(W1[idx]);
    } else if (b < 128) {                 // Wg
        int idx = (b - 64) * 256 + t;
        int k = idx >> 7, n = idx & 127;
        Wgt[n * 128 + k] = f2b(Wg[idx]);
    } else if (b < 384) {                 // Wa [128][512] -> [512][128]
        int idx = (b - 128) * 256 + t;
        int k = idx >> 9, n = idx & 511;
        Wat[(size_t)n * 128 + k] = f2b(Wa[idx]);
    } else if (b < 512) {                 // Wp [256][128] -> [128][256]
        int idx = (b - 384) * 256 + t;
        int k = idx >> 7, n = idx & 127;
        Wpt[(size_t)n * 256 + k] = f2b(Wp[idx]);
    } else {                              // bucket histogram
        __shared__ int lh[NB];
        int blk = b - 512;
        bool loc = blk < 196;
        const int* dstp = loc ? ldst : gdst;
        int nE = loc ? EL : EG;
        int* gh = ghist + (loc ? 0 : NB);
        int start = (loc ? blk : blk - 196) * 4096;
        if (t < NB) lh[t] = 0;
        __syncthreads();
        #pragma unroll
        for (int i = 0; i < 16; i++) {
            int e = start + i * 256 + t;
            if (e < nE) atomicAdd(&lh[dstp[e] >> 8], 1);
        }
        __syncthreads();
        if (t < NB && lh[t]) atomicAdd(&gh[t], lh[t]);
    }
}
// exclusive scan of bucket counts; init cursors
__global__ void bucket_scan(const int* __restrict__ ghist,
                            int* __restrict__ bbase, int* __restrict__ gcur)
{
    __shared__ int s[256];
    int g = blockIdx.x, t = threadIdx.x;
    int v = (t < NB) ? ghist[g * NB + t] : 0;
    s[t] = v;
    __syncthreads();
    for (int off = 1; off < 256; off <<= 1) {
        int u = (t >= off) ? s[t - off] : 0;
        __syncthreads();
        s[t] += u;
        __syncthreads();
    }
    if (t < NB) {
        bbase[g * (NB + 1) + t] = s[t] - v;
        gcur[g * NB + t] = s[t] - v;
    }
    if (t == NB - 1) bbase[g * (NB + 1) + NB] = s[t];
}
// partition edges into bucket-contiguous ebuf
__global__ __launch_bounds__(256) void bucket_part(
    const int* __restrict__ lsrc, const int* __restrict__ ldst,
    const int* __restrict__ gsrc, const int* __restrict__ gdst,
    int* __restrict__ gcur, unsigned* __restrict__ ebuf_l, unsigned* __restrict__ ebuf_g)
{
    __shared__ int lhist[NB], lbase[NB];
    int blk = blockIdx.x, t = threadIdx.x;
    bool loc = blk < 196;
    const int* srcp = loc ? lsrc : gsrc;
    const int* dstp = loc ? ldst : gdst;
    int nE = loc ? EL : EG;
    unsigned* ebuf = loc ? ebuf_l : ebuf_g;
    int* cur = gcur + (loc ? 0 : NB);
    int start = (loc ? blk : blk - 196) * 4096;
    if (t < NB) lhist[t] = 0;
    __syncthreads();
    unsigned pk[16];
    #pragma unroll
    for (int i = 0; i < 16; i++) {
        int e = start + i * 256 + t;
        if (e < nE) {
            unsigned d = (unsigned)dstp[e];
            pk[i] = (d << 16) | (unsigned)srcp[e];
            atomicAdd(&lhist[d >> 8], 1);
        } else pk[i] = 0xFFFFFFFFu;
    }
    __syncthreads();
    if (t < NB) lbase[t] = atomicAdd(&cur[t], lhist[t]);
    __syncthreads();
    if (t < NB) lhist[t] = 0;
    __syncthreads();
    #pragma unroll
    for (int i = 0; i < 16; i++) {
        unsigned b = pk[i] >> 24;
        if (b < NB) {
            int r = atomicAdd(&lhist[b], 1);
            ebuf[lbase[b] + r] = pk[i];
        }
    }
}
// per-bucket fine CSR
__global__ __launch_bounds__(256) void bucket_csr(
    const unsigned* __restrict__ ebuf_l, const unsigned* __restrict__ ebuf_g,
    const int* __restrict__ bbase,
    int* __restrict__ offs_l, int* __restrict__ offs_g,
    unsigned short* __restrict__ csr_l, unsigned short* __restrict__ csr_g,
    float* __restrict__ dinv)
{
    __shared__ int cnt[256], s[256], cur[256];
    int blk = blockIdx.x, t = threadIdx.x;
    bool loc = blk < 196;
    int b = loc ? blk : blk - 196;
    const unsigned* ebuf = loc ? ebuf_l : ebuf_g;
    const int* bb = bbase + (loc ? 0 : NB + 1);
    int* offs = loc ? offs_l : offs_g;
    unsigned short* csr = loc ? csr_l : csr_g;
    int rs = bb[b], re = bb[b + 1];
    cnt[t] = 0;
    __syncthreads();
    for (int i = rs + t; i < re; i += 256) atomicAdd(&cnt[(ebuf[i] >> 16) & 255], 1);
    __syncthreads();
    int v = cnt[t];
    s[t] = v;
    __syncthreads();
    for (int off = 1; off < 256; off <<= 1) {
        int u = (t >= off) ? s[t - off] : 0;
        __syncthreads();
        s[t] += u;
        __syncthreads();
    }
    int excl = s[t] - v;
    int node = b * 256 + t;
    cur[t] = rs + excl;
    if (node < N_NODES) {
        offs[node] = rs + excl;
        if (loc) dinv[node] = rsqrtf((float)(v + 1));
    }
    if (blk == 0 && t == 0) offs_l[N_NODES] = EL;
    if (blk == 196 && t == 0) offs_g[N_NODES] = EG;
    __syncthreads();
    for (int i = rs + t; i < re; i += 256) {
        unsigned pk = ebuf[i];
        int r = atomicAdd(&cur[(pk >> 16) & 255], 1);
        csr[r] = (unsigned short)(pk & 0xFFFFu);
    }
}

// ---------- MFMA GEMM, f32 A in (converted during staging): x_local = relu(x@W1+b1), bf16 out ----------
__global__ __launch_bounds__(256) void gemm_x(
    const float* __restrict__ A, const unsigned short* __restrict__ Bt,
    const float* __restrict__ bias, unsigned short* __restrict__ out, int M)
{
    __shared__ unsigned short As[128 * 128];
    __shared__ unsigned short Bs[128 * 128];
    int tid = threadIdx.x;
    int lane = tid & 63, w = tid >> 6;
    int wr = w >> 1, wc = w & 1;
    int l16 = lane & 15, lhi = lane >> 4;
    int m0 = blockIdx.x * 128;
    f32x4 acc[4][4] = {};
    #pragma unroll
    for (int i = 0; i < 8; i++) {
        int u = tid + i * 256;
        int row = u >> 4, e0 = (u & 15) << 3;
        int sw = e0 ^ ((row & 7) << 3);
        int gr = m0 + row;
        unsigned short pb[8] = {};
        if (gr < M) {
            float4 a0 = *(const float4*)(A + (size_t)gr * 128 + e0);
            float4 a1 = *(const float4*)(A + (size_t)gr * 128 + e0 + 4);
            pb[0] = f2b(a0.x); pb[1] = f2b(a0.y); pb[2] = f2b(a0.z); pb[3] = f2b(a0.w);
            pb[4] = f2b(a1.x); pb[5] = f2b(a1.y); pb[6] = f2b(a1.z); pb[7] = f2b(a1.w);
        }
        *(bf16x8*)(As + row * 128 + sw) = *(bf16x8*)pb;
        bf16x8 vb = *(const bf16x8*)(Bt + (size_t)row * 128 + e0);
        *(bf16x8*)(Bs + row * 128 + sw) = vb;
    }
    __syncthreads();
    #pragma unroll
    for (int kk = 0; kk < 4; kk++) {
        int ke = kk * 32 + lhi * 8;
        bf16x8 af[4], bfr[4];
        #pragma unroll
        for (int m = 0; m < 4; m++) {
            int r = wr * 64 + m * 16 + l16;
            af[m] = *(const bf16x8*)(As + r * 128 + (ke ^ ((r & 7) << 3)));
        }
        #pragma unroll
        for (int n = 0; n < 4; n++) {
            int r = wc * 64 + n * 16 + l16;
            bfr[n] = *(const bf16x8*)(Bs + r * 128 + (ke ^ ((r & 7) << 3)));
        }
        #pragma unroll
        for (int m = 0; m < 4; m++)
            #pragma unroll
            for (int n = 0; n < 4; n++)
                acc[m][n] = __builtin_amdgcn_mfma_f32_16x16x32_bf16(af[m], bfr[n], acc[m][n], 0, 0, 0);
    }
    #pragma unroll
    for (int m = 0; m < 4; m++) {
        #pragma unroll
        for (int r = 0; r < 4; r++) {
            int row_g = m0 + wr * 64 + m * 16 + lhi * 4 + r;
            if (row_g >= M) continue;
            #pragma unroll
            for (int n = 0; n < 4; n++) {
                int col_g = wc * 64 + n * 16 + l16;
                float v = fmaxf(acc[m][n][r] + bias[col_g], 0.f);
                out[(size_t)row_g * 128 + col_g] = f2b(v);
            }
        }
    }
}

// ---------- fused Wg + Wa GEMMs, fp8 out; attn coefficients for Wa heads ----------
// grid (GB, 5): y=0 -> xw_g; y=1..4 -> head y-1 of xw_a (+a_s/a_d epilogue)
__global__ __launch_bounds__(256) void gemm_gw(
    const unsigned short* __restrict__ A, const unsigned short* __restrict__ Wgt,
    const unsigned short* __restrict__ Wat,
    unsigned char* __restrict__ xw_g8, unsigned char* __restrict__ xw_a8, int M,
    const float* __restrict__ atts, const float* __restrict__ attd,
    float* __restrict__ a_s, float* __restrict__ a_d)
{
    __shared__ unsigned short As[128 * 128];
    __shared__ unsigned short Bs[128 * 128];
    __shared__ float sas[128], sad[128];
    int tid = threadIdx.x;
    int lane = tid & 63, w = tid >> 6;
    int wr = w >> 1, wc = w & 1;
    int l16 = lane & 15, lhi = lane >> 4;
    int m0 = blockIdx.x * 128;
    int hy = (int)blockIdx.y - 1;            // -1 = GCN path, 0..3 = head
    const unsigned short* Bt = (hy < 0) ? Wgt : (Wat + (size_t)hy * 128 * 128);
    f32x4 acc[4][4] = {};
    #pragma unroll
    for (int i = 0; i < 8; i++) {
        int u = tid + i * 256;
        int row = u >> 4, e0 = (u & 15) << 3;
        int sw = e0 ^ ((row & 7) << 3);
        bf16x8 va = {};
        int gr = m0 + row;
        if (gr < M) va = *(const bf16x8*)(A + (size_t)gr * 128 + e0);
        *(bf16x8*)(As + row * 128 + sw) = va;
        bf16x8 vb = *(const bf16x8*)(Bt + (size_t)row * 128 + e0);
        *(bf16x8*)(Bs + row * 128 + sw) = vb;
    }
    if (tid < 128) { sas[tid] = 0.f; sad[tid] = 0.f; }
    __syncthreads();
    #pragma unroll
    for (int kk = 0; kk < 4; kk++) {
        int ke = kk * 32 + lhi * 8;
        bf16x8 af[4], bfr[4];
        #pragma unroll
        for (int m = 0; m < 4; m++) {
            int r = wr * 64 + m * 16 + l16;
            af[m] = *(const bf16x8*)(As + r * 128 + (ke ^ ((r & 7) << 3)));
        }
        #pragma unroll
        for (int n = 0; n < 4; n++) {
            int r = wc * 64 + n * 16 + l16;
            bfr[n] = *(const bf16x8*)(Bs + r * 128 + (ke ^ ((r & 7) << 3)));
        }
        #pragma unroll
        for (int m = 0; m < 4; m++)
            #pragma unroll
            for (int n = 0; n < 4; n++)
                acc[m][n] = __builtin_amdgcn_mfma_f32_16x16x32_bf16(af[m], bfr[n], acc[m][n], 0, 0, 0);
    }
    if (hy < 0) {
        #pragma unroll
        for (int m = 0; m < 4; m++)
            #pragma unroll
            for (int r = 0; r < 4; r++) {
                int row_g = m0 + wr * 64 + m * 16 + lhi * 4 + r;
                if (row_g >= M) continue;
                #pragma unroll
                for (int n = 0; n < 4; n++) {
                    int col_g = wc * 64 + n * 16 + l16;
                    xw_g8[(size_t)row_g * 128 + col_g] = f2fp8(acc[m][n][r]);
                }
            }
    } else {
        float ats[4], atd[4];
        #pragma unroll
        for (int n = 0; n < 4; n++) {
            int cl = wc * 64 + n * 16 + l16;
            ats[n] = atts[hy * 128 + cl];
            atd[n] = attd[hy * 128 + cl];
        }
        #pragma unroll
        for (int m = 0; m < 4; m++) {
            #pragma unroll
            for (int r = 0; r < 4; r++) {
                int row_l = wr * 64 + m * 16 + lhi * 4 + r;
                int row_g = m0 + row_l;
                float ps = 0.f, pd = 0.f;
                #pragma unroll
                for (int n = 0; n < 4; n++) {
                    float v = acc[m][n][r];
                    ps = fmaf(v, ats[n], ps);
                    pd = fmaf(v, atd[n], pd);
                    if (row_g < M) {
                        int col_g = hy * 128 + wc * 64 + n * 16 + l16;
                        xw_a8[(size_t)row_g * 512 + col_g] = f2fp8(v);
                    }
                }
                #pragma unroll
                for (int off = 1; off < 16; off <<= 1) {
                    ps += __shfl_xor(ps, off);
                    pd += __shfl_xor(pd, off);
                }
                if (l16 == 0) {
                    atomicAdd(&sas[row_l], ps);
                    atomicAdd(&sad[row_l], pd);
                }
            }
        }
        __syncthreads();
        if (tid < 128) {
            int row_g = m0 + tid;
            if (row_g < M) {
                a_s[(size_t)row_g * 4 + hy] = sas[tid];
                a_d[(size_t)row_g * 4 + hy] = sad[tid];
            }
        }
    }
}

// ---------- fused gathers (fp8 operands; GAT softmax in-wave) ----------
__global__ __launch_bounds__(256) void fused_gather(
    const int* __restrict__ offs_l, const unsigned short* __restrict__ csr_l,
    const unsigned char* __restrict__ xw_g8, const float* __restrict__ dinv,
    const float* __restrict__ bg,
    const int* __restrict__ offs_g, const unsigned short* __restrict__ csr_g,
    const float* __restrict__ a_s, const float* __restrict__ a_d,
    const unsigned char* __restrict__ xw_a8, const float* __restrict__ ba,
    unsigned short* __restrict__ xcomb)
{
    int blk = blockIdx.x;
    int lane = threadIdx.x & 63;
    int c2 = lane * 2;
    if (blk < 12500) {
        // ---- GCN ----
        int d = (blk * 256 + threadIdx.x) >> 6;
        if (d >= N_NODES) return;
        const unsigned short* xg = (const unsigned short*)xw_g8;   // 64 ushort/row
        int base = offs_l[d], end = offs_l[d + 1];
        float ax = 0.f, ay = 0.f;
        for (int i = base; i < end; ) {
            int chunk = min(64, end - i);
            int sv = 0; float dvv = 0.f;
            if (lane < chunk) { sv = csr_l[i + lane]; dvv = dinv[sv]; }
            int j = 0;
            for (; j + 8 <= chunk; j += 8) {
                #pragma unroll
                for (int q = 0; q < 8; q++) {
                    int s = __shfl(sv, j + q);
                    float dv = __shfl(dvv, j + q);
                    f32x2 v = fp8x2_to_f32(xg[(size_t)s * 64 + lane]);
                    ax = fmaf(v[0], dv, ax);
                    ay = fmaf(v[1], dv, ay);
                }
            }
            for (; j < chunk; j++) {
                int s = __shfl(sv, j);
                float dv = __shfl(dvv, j);
                f32x2 v = fp8x2_to_f32(xg[(size_t)s * 64 + lane]);
                ax = fmaf(v[0], dv, ax);
                ay = fmaf(v[1], dv, ay);
            }
            i += chunk;
        }
        float dd = dinv[d];
        f32x2 sv2 = fp8x2_to_f32(xg[(size_t)d * 64 + lane]);
        float ox = fmaxf(dd * ax + dd * dd * sv2[0] + bg[c2], 0.f);
        float oy = fmaxf(dd * ay + dd * dd * sv2[1] + bg[c2 + 1], 0.f);
        unsigned uo = (unsigned)f2b(ox) | ((unsigned)f2b(oy) << 16);
        *(unsigned*)(xcomb + (size_t)d * 256 + c2) = uo;
    } else {
        // ---- GAT (softmax in-wave) ----
        int d = ((blk - 12500) * 256 + threadIdx.x) >> 6;
        if (d >= N_NODES) return;
        const unsigned short* xa = (const unsigned short*)xw_a8;   // 256 ushort/row
        int base = offs_g[d], end = offs_g[d + 1];
        int deg = end - base;
        float4 ad4 = *(const float4*)(a_d + (size_t)d * 4);
        float4 asd = *(const float4*)(a_s + (size_t)d * 4);
        float es0 = lrelu(asd.x + ad4.x), es1 = lrelu(asd.y + ad4.y);
        float es2 = lrelu(asd.z + ad4.z), es3 = lrelu(asd.w + ad4.w);
        float ax = 0.f, ay = 0.f;
        float m0, m1, m2, m3, r0, r1, r2, r3;
        if (deg <= 64) {
            int sv = 0;
            float e0 = -1e30f, e1 = -1e30f, e2 = -1e30f, e3 = -1e30f;
            if (lane < deg) {
                sv = csr_g[base + lane];
                float4 s4 = *(const float4*)(a_s + (size_t)sv * 4);
                e0 = lrelu(s4.x + ad4.x); e1 = lrelu(s4.y + ad4.y);
                e2 = lrelu(s4.z + ad4.z); e3 = lrelu(s4.w + ad4.w);
            }
            m0 = e0; m1 = e1; m2 = e2; m3 = e3;
            #pragma unroll
            for (int off = 1; off < 64; off <<= 1) {
                m0 = fmaxf(m0, __shfl_xor(m0, off));
                m1 = fmaxf(m1, __shfl_xor(m1, off));
                m2 = fmaxf(m2, __shfl_xor(m2, off));
                m3 = fmaxf(m3, __shfl_xor(m3, off));
            }
            m0 = fmaxf(m0, es0); m1 = fmaxf(m1, es1);
            m2 = fmaxf(m2, es2); m3 = fmaxf(m3, es3);
            float w0 = (lane < deg) ? __expf(e0 - m0) : 0.f;
            float w1 = (lane < deg) ? __expf(e1 - m1) : 0.f;
            float w2 = (lane < deg) ? __expf(e2 - m2) : 0.f;
            float w3 = (lane < deg) ? __expf(e3 - m3) : 0.f;
            float d0 = w0, d1 = w1, d2 = w2, d3 = w3;
            #pragma unroll
            for (int off = 1; off < 64; off <<= 1) {
                d0 += __shfl_xor(d0, off); d1 += __shfl_xor(d1, off);
                d2 += __shfl_xor(d2, off); d3 += __shfl_xor(d3, off);
            }
            d0 += __expf(es0 - m0); d1 += __expf(es1 - m1);
            d2 += __expf(es2 - m2); d3 += __expf(es3 - m3);
            r0 = 1.f / (d0 + 1e-16f); r1 = 1.f / (d1 + 1e-16f);
            r2 = 1.f / (d2 + 1e-16f); r3 = 1.f / (d3 + 1e-16f);
            for (int j = 0; j < deg; j++) {
                int s = __shfl(sv, j);
                float a0 = __shfl(w0, j) * r0, a1 = __shfl(w1, j) * r1;
                float a2 = __shfl(w2, j) * r2, a3 = __shfl(w3, j) * r3;
                const unsigned short* row = xa + (size_t)s * 256 + lane;
                f32x2 v0 = fp8x2_to_f32(row[0]);
                f32x2 v1 = fp8x2_to_f32(row[64]);
                f32x2 v2 = fp8x2_to_f32(row[128]);
                f32x2 v3 = fp8x2_to_f32(row[192]);
                ax = fmaf(v0[0], a0, ax); ay = fmaf(v0[1], a0, ay);
                ax = fmaf(v1[0], a1, ax); ay = fmaf(v1[1], a1, ay);
                ax = fmaf(v2[0], a2, ax); ay = fmaf(v2[1], a2, ay);
                ax = fmaf(v3[0], a3, ax); ay = fmaf(v3[1], a3, ay);
            }
        } else {
            // general fallback (deg > 64): 3-pass with reload
            m0 = es0; m1 = es1; m2 = es2; m3 = es3;
            for (int i = base; i < end; i += 64) {
                int c = min(64, end - i);
                float t0 = -1e30f, t1 = -1e30f, t2 = -1e30f, t3 = -1e30f;
                if (lane < c) {
                    int s = csr_g[i + lane];
                    float4 s4 = *(const float4*)(a_s + (size_t)s * 4);
                    t0 = lrelu(s4.x + ad4.x); t1 = lrelu(s4.y + ad4.y);
                    t2 = lrelu(s4.z + ad4.z); t3 = lrelu(s4.w + ad4.w);
                }
                m0 = fmaxf(m0, t0); m1 = fmaxf(m1, t1);
                m2 = fmaxf(m2, t2); m3 = fmaxf(m3, t3);
            }
            #pragma unroll
            for (int off = 1; off < 64; off <<= 1) {
                m0 = fmaxf(m0, __shfl_xor(m0, off));
                m1 = fmaxf(m1, __shfl_xor(m1, off));
                m2 = fmaxf(m2, __shfl_xor(m2, off));
                m3 = fmaxf(m3, __shfl_xor(m3, off));
            }
            float d0 = 0.f, d1 = 0.f, d2 = 0.f, d3 = 0.f;
            for (int i = base; i < end; i += 64) {
                int c = min(64, end - i);
                if (lane < c) {
                    int s = csr_g[i + lane];
                    float4 s4 = *(const float4*)(a_s + (size_t)s * 4);
                    d0 += __expf(lrelu(s4.x + ad4.x) - m0);
                    d1 += __expf(lrelu(s4.y + ad4.y) - m1);
                    d2 += __expf(lrelu(s4.z + ad4.z) - m2);
                    d3 += __expf(lrelu(s4.w + ad4.w) - m3);
                }
            }
            #pragma unroll
            for (int off = 1; off < 64; off <<= 1) {
                d0 += __shfl_xor(d0, off); d1 += __shfl_xor(d1, off);
                d2 += __shfl_xor(d2, off); d3 += __shfl_xor(d3, off);
            }
            d0 += __expf(es0 - m0); d1 += __expf(es1 - m1);
            d2 += __expf(es2 - m2); d3 += __expf(es3 - m3);
            r0 = 1.f / (d0 + 1e-16f); r1 = 1.f / (d1 + 1e-16f);
            r2 = 1.f / (d2 + 1e-16f); r3 = 1.f / (d3 + 1e-16f);
            for (int i = base; i < end; i += 64) {
                int c = min(64, end - i);
                int sv = 0;
                float w0 = 0.f, w1 = 0.f, w2 = 0.f, w3 = 0.f;
                if (lane < c) {
                    sv = csr_g[i + lane];
                    float4 s4 = *(const float4*)(a_s + (size_t)sv * 4);
                    w0 = __expf(lrelu(s4.x + ad4.x) - m0) * r0;
                    w1 = __expf(lrelu(s4.y + ad4.y) - m1) * r1;
                    w2 = __expf(lrelu(s4.z + ad4.z) - m2) * r2;
                    w3 = __expf(lrelu(s4.w + ad4.w) - m3) * r3;
                }
                for (int j = 0; j < c; j++) {
                    int s = __shfl(sv, j);
                    float a0 = __shfl(w0, j), a1 = __shfl(w1, j);
                    float a2 = __shfl(w2, j), a3 = __shfl(w3, j);
                    const unsigned short* row = xa + (size_t)s * 256 + lane;
                    f32x2 v0 = fp8x2_to_f32(row[0]);
                    f32x2 v1 = fp8x2_to_f32(row[64]);
                    f32x2 v2 = fp8x2_to_f32(row[128]);
                    f32x2 v3 = fp8x2_to_f32(row[192]);
                    ax = fmaf(v0[0], a0, ax); ay = fmaf(v0[1], a0, ay);
                    ax = fmaf(v1[0], a1, ax); ay = fmaf(v1[1], a1, ay);
                    ax = fmaf(v2[0], a2, ax); ay = fmaf(v2[1], a2, ay);
                    ax = fmaf(v3[0], a3, ax); ay = fmaf(v3[1], a3, ay);
                }
            }
        }
        // self term
        float s0 = __expf(es0 - m0) * r0, s1 = __expf(es1 - m1) * r1;
        float s2 = __expf(es2 - m2) * r2, s3 = __expf(es3 - m3) * r3;
        const unsigned short* row = xa + (size_t)d * 256 + lane;
        f32x2 v0 = fp8x2_to_f32(row[0]);
        f32x2 v1 = fp8x2_to_f32(row[64]);
        f32x2 v2 = fp8x2_to_f32(row[128]);
        f32x2 v3 = fp8x2_to_f32(row[192]);
        ax = fmaf(v0[0], s0, ax); ay = fmaf(v0[1], s0, ay);
        ax = fmaf(v1[0], s1, ax); ay = fmaf(v1[1], s1, ay);
        ax = fmaf(v2[0], s2, ax); ay = fmaf(v2[1], s2, ay);
        ax = fmaf(v3[0], s3, ax); ay = fmaf(v3[1], s3, ay);
        float ox = fmaxf(0.25f * ax + ba[c2], 0.f);
        float oy = fmaxf(0.25f * ay + ba[c2 + 1], 0.f);
        unsigned uo = (unsigned)f2b(ox) | ((unsigned)f2b(oy) << 16);
        *(unsigned*)(xcomb + (size_t)d * 256 + 128 + c2) = uo;
    }
}

// ---------- MFMA pooled GEMM + column-mean accumulation (K=256, N=128) ----------
__global__ __launch_bounds__(256) void mfma_pool(
    const unsigned short* __restrict__ A, const unsigned short* __restrict__ Bt,
    const float* __restrict__ bp, float* __restrict__ sumvec, int M)
{
    __shared__ unsigned short As[128 * 128];
    __shared__ unsigned short Bs[128 * 128];
    __shared__ float red[128];
    int tid = threadIdx.x;
    int lane = tid & 63, w = tid >> 6;
    int wr = w >> 1, wc = w & 1;
    int l16 = lane & 15, lhi = lane >> 4;
    int m0 = blockIdx.x * 128;
    f32x4 acc[4][4] = {};
    for (int kb = 0; kb < 256; kb += 128) {
        if (kb) __syncthreads();
        #pragma unroll
        for (int i = 0; i < 8; i++) {
            int u = tid + i * 256;
            int row = u >> 4, e0 = (u & 15) << 3;
            int sw = e0 ^ ((row & 7) << 3);
            bf16x8 va = {};
            int gr = m0 + row;
            if (gr < M) va = *(const bf16x8*)(A + (size_t)gr * 256 + kb + e0);
            *(bf16x8*)(As + row * 128 + sw) = va;
            bf16x8 vb = *(const bf16x8*)(Bt + (size_t)row * 256 + kb + e0);
            *(bf16x8*)(Bs + row * 128 + sw) = vb;
        }
        __syncthreads();
        #pragma unroll
        for (int kk = 0; kk < 4; kk++) {
            int ke = kk * 32 + lhi * 8;
            bf16x8 af[4], bfr[4];
            #pragma unroll
            for (int m = 0; m < 4; m++) {
                int r = wr * 64 + m * 16 + l16;
                af[m] = *(const bf16x8*)(As + r * 128 + (ke ^ ((r & 7) << 3)));
            }
            #pragma unroll
            for (int n = 0; n < 4; n++) {
                int r = wc * 64 + n * 16 + l16;
                bfr[n] = *(const bf16x8*)(Bs + r * 128 + (ke ^ ((r & 7) << 3)));
            }
            #pragma unroll
            for (int m = 0; m < 4; m++)
                #pragma unroll
                for (int n = 0; n < 4; n++)
                    acc[m][n] = __builtin_amdgcn_mfma_f32_16x16x32_bf16(af[m], bfr[n], acc[m][n], 0, 0, 0);
        }
    }
    float bcol[4];
    #pragma unroll
    for (int n = 0; n < 4; n++) bcol[n] = bp[wc * 64 + n * 16 + l16];
    float colsum[4] = {0.f, 0.f, 0.f, 0.f};
    #pragma unroll
    for (int m = 0; m < 4; m++) {
        #pragma unroll
        for (int r = 0; r < 4; r++) {
            int row_g = m0 + wr * 64 + m * 16 + lhi * 4 + r;
            if (row_g < M) {
                #pragma unroll
                for (int n = 0; n < 4; n++)
                    colsum[n] += fmaxf(acc[m][n][r] + bcol[n], 0.f);
            }
        }
    }
    #pragma unroll
    for (int n = 0; n < 4; n++) {
        colsum[n] += __shfl_xor(colsum[n], 16);
        colsum[n] += __shfl_xor(colsum[n], 32);
    }
    if (tid < 128) red[tid] = 0.f;
    __syncthreads();
    if (lhi == 0) {
        #pragma unroll
        for (int n = 0; n < 4; n++)
            atomicAdd(&red[wc * 64 + n * 16 + l16], colsum[n]);
    }
    __syncthreads();
    if (tid < 128) atomicAdd(&sumvec[tid], red[tid]);
}

// ---------- final heads (f32 output) ----------
__global__ void final_head(const float* __restrict__ sumvec,
                           const float* __restrict__ Wc1, const float* __restrict__ bc1,
                           const float* __restrict__ Wc2, const float* __restrict__ bc2,
                           const float* __restrict__ Wu, const float* __restrict__ bu,
                           float* __restrict__ out)
{
    __shared__ float xf[128];
    __shared__ float h1[64];
    int t = threadIdx.x;   // 128 threads
    xf[t] = sumvec[t] * (1.0f / N_NODES);
    __syncthreads();
    if (t < 64) {
        float s = bc1[t];
        for (int c = 0; c < 128; c++) s = fmaf(xf[c], Wc1[c * 64 + t], s);
        h1[t] = fmaxf(s, 0.f);
    }
    __syncthreads();
    if (t < 16) {
        float s = bc2[t];
        for (int j = 0; j < 64; j++) s = fmaf(h1[j], Wc2[j * 16 + t], s);
        out[t] = s;
        float u = bu[t];
        for (int c = 0; c < 128; c++) u = fmaf(xf[c], Wu[c * 16 + t], u);
        out[16 + t] = 1.0f / (1.0f + expf(-u));
    }
}

extern "C" void kernel_launch(void* const* d_in, const int* in_sizes, int n_in,
                              void* d_out, int out_size, void* d_ws, size_t ws_size,
                              hipStream_t stream) {
    const float* x    = (const float*)d_in[0];
    const int*   lei  = (const int*)d_in[1];
    const int*   gei  = (const int*)d_in[2];
    const float* W1   = (const float*)d_in[3];
    const float* b1   = (const float*)d_in[4];
    const float* Wg   = (const float*)d_in[5];
    const float* bg   = (const float*)d_in[6];
    const float* Wa   = (const float*)d_in[7];
    const float* atts = (const float*)d_in[8];
    const float* attd = (const float*)d_in[9];
    const float* ba   = (const float*)d_in[10];
    const float* Wp   = (const float*)d_in[11];
    const float* bp   = (const float*)d_in[12];
    const float* Wc1  = (const float*)d_in[13];
    const float* bc1  = (const float*)d_in[14];
    const float* Wc2  = (const float*)d_in[15];
    const float* bc2  = (const float*)d_in[16];
    const float* Wu   = (const float*)d_in[17];
    const float* bu   = (const float*)d_in[18];

    const int* lsrc = lei;
    const int* ldst = lei + EL;
    const int* gsrc = gei;
    const int* gdst = gei + EG;

    uintptr_t base = (uintptr_t)d_ws;
    auto alloc = [&](size_t bytes) { void* p = (void*)base; base += (bytes + 255) & ~(size_t)255; return p; };
    unsigned short* x_loc  = (unsigned short*)alloc((size_t)N_NODES * 128 * 2);
    unsigned char*  xw_g8  = (unsigned char*)alloc((size_t)N_NODES * 128);
    unsigned char*  xw_a8  = (unsigned char*)alloc((size_t)N_NODES * 512);
    unsigned short* xcomb  = (unsigned short*)alloc((size_t)N_NODES * 256 * 2);
    unsigned short* W1t    = (unsigned short*)alloc((size_t)128 * 128 * 2);
    unsigned short* Wgt    = (unsigned short*)alloc((size_t)128 * 128 * 2);
    unsigned short* Wat    = (unsigned short*)alloc((size_t)512 * 128 * 2);
    unsigned short* Wpt    = (unsigned short*)alloc((size_t)128 * 256 * 2);
    float* dinv       = (float*)alloc((size_t)N_NODES * 4);
    float* a_s        = (float*)alloc((size_t)N_NODES * 4 * 4);
    float* a_d        = (float*)alloc((size_t)N_NODES * 4 * 4);
    int*   ghist      = (int*)alloc((size_t)2 * NB * 4);
    int*   bbase      = (int*)alloc((size_t)2 * (NB + 1) * 4);
    int*   gcur       = (int*)alloc((size_t)2 * NB * 4);
    unsigned* ebuf_l  = (unsigned*)alloc((size_t)EL * 4);
    unsigned* ebuf_g  = (unsigned*)alloc((size_t)EG * 4);
    int*   offs_l     = (int*)alloc(((size_t)N_NODES + 1) * 4);
    int*   offs_g     = (int*)alloc(((size_t)N_NODES + 1) * 4);
    unsigned short* csr_l = (unsigned short*)alloc((size_t)EL * 2);
    unsigned short* csr_g = (unsigned short*)alloc((size_t)EG * 2);
    float* sumvec     = (float*)alloc(128 * 4);

    hipMemsetAsync(ghist, 0, (size_t)2 * NB * 4, stream);
    hipMemsetAsync(sumvec, 0, 128 * 4, stream);

    // weights -> bf16^T + bucket histogram (512 conv blocks + 245 hist blocks)
    conv_hist<<<757, 256, 0, stream>>>(W1, W1t, Wg, Wgt, Wa, Wat, Wp, Wpt,
                                       ldst, gdst, ghist);
    bucket_scan<<<2, 256, 0, stream>>>(ghist, bbase, gcur);
    bucket_part<<<245, 256, 0, stream>>>(lsrc, ldst, gsrc, gdst, gcur, ebuf_l, ebuf_g);
    bucket_csr<<<392, 256, 0, stream>>>(ebuf_l, ebuf_g, bbase, offs_l, offs_g,
                                        csr_l, csr_g, dinv);

    // x_local = relu(x @ W1 + b1)   (f32 A converted during staging)
    gemm_x<<<GB, 256, 0, stream>>>(x, W1t, b1, x_loc, N_NODES);

    // Wg GEMM (fp8 out) + Wa GEMM (fp8 out, attn coefficients) in one dispatch
    gemm_gw<<<dim3(GB, 5), 256, 0, stream>>>(x_loc, Wgt, Wat, xw_g8, xw_a8, N_NODES,
                                             atts, attd, a_s, a_d);

    // both gathers (GAT softmax in-wave)
    fused_gather<<<25000, 256, 0, stream>>>(offs_l, csr_l, xw_g8, dinv, bg,
                                            offs_g, csr_g, a_s, a_d, xw_a8, ba, xcomb);

    // pool + heads
    mfma_pool<<<GB, 256, 0, stream>>>(xcomb, Wpt, bp, sumvec, N_NODES);
    final_head<<<1, 128, 0, stream>>>(sumvec, Wc1, bc1, Wc2, bc2, Wu, bu,
                                      (float*)d_out);
}